// Round 3
// baseline (13699.376 us; speedup 1.0000x reference)
//
#include <hip/hip_runtime.h>

// ---------------- problem constants ----------------
#define TT 100
#define HH 256
#define NSTEP 8
__device__ __constant__ float kDT_SC = 1.0f / 24.0f;
#define HS (0.125f)          // 1/NSTEP

// ---------------- d_ws layout (floats) ----------------
#define OFF_WHH1T4   0         // [64][256][4]
#define OFF_WIH1T    65536     // [20][256]
#define OFF_WIH2AT   70656     // [8][256]
#define OFF_WIH2BT4  72704     // [64][256][4]
#define OFF_WHH2T4   138240    // [64][256][4]
#define OFF_OW1T4    203776    // [64][256][4]
#define OFF_IW1T4    269312    // [64][256][4]
#define OFF_FW1R     334848    // [64][256] row-major, zero-padded rows >= 50
#define OFF_FW2T4    351232    // [13][256][4]
#define OFF_B1C      364544    // [256] bih1+bhh1
#define OFF_B2C      364800    // [256] bih2+bhh2
#define WS_FLOATS    365056

// ---------------- LDS layout (floats) ----------------
#define L_YCUR  0        // 4 rows * 272 (4 chunks of 68 = 64 data + 4 pad)
#define L_Z     1088     // 4 states * 64
#define L_HC2   1344     // 2 * 256
#define L_XA    1856     // 2 * 28
#define L_TR    1912     // 2
#define L_RED   1914     // 16
#define L_TOTAL 1930

__device__ __forceinline__ float fast_tanh(float v) {
    float e = __expf(2.0f * v);
    return 1.0f - 2.0f / (e + 1.0f);
}
__device__ __forceinline__ void fma4(float4& a, const float4 w, const float4 h) {
    a.x = fmaf(w.x, h.x, a.x); a.y = fmaf(w.y, h.y, a.y);
    a.z = fmaf(w.z, h.z, a.z); a.w = fmaf(w.w, h.w, a.w);
}
__device__ __forceinline__ float rsum4(const float4 a) { return (a.x + a.y) + (a.z + a.w); }
// padded ycur indexing: row v has 4 chunks of 68 floats (64 valid + 4 pad)
__device__ __forceinline__ int yoffF(int v, int j) { return v * 272 + (j >> 6) * 68 + (j & 63); }
__device__ __forceinline__ int yoff4(int v, int jb) { return v * 68 + (jb >> 4) * 17 + (jb & 15); }

// ================= setup: repack weights into d_ws =================
__global__ void codernn_setup(const float* __restrict__ Wih1, const float* __restrict__ Whh1,
                              const float* __restrict__ bih1, const float* __restrict__ bhh1,
                              const float* __restrict__ Wih2, const float* __restrict__ Whh2,
                              const float* __restrict__ bih2, const float* __restrict__ bhh2,
                              const float* __restrict__ oW1, const float* __restrict__ iW1,
                              const float* __restrict__ fW1, const float* __restrict__ fW2,
                              float* __restrict__ ws) {
    int e = blockIdx.x * 256 + threadIdx.x;
    if (e >= WS_FLOATS) return;
    float v;
    if (e < OFF_WIH1T) {                 // Whh1T4
        int q = e; int jb = q >> 10, i = (q >> 2) & 255, dj = q & 3;
        v = Whh1[i * 256 + jb * 4 + dj];
    } else if (e < OFF_WIH2AT) {         // Wih1T [20][256]
        int q = e - OFF_WIH1T; int j = q >> 8, i = q & 255;
        v = (j < 19) ? Wih1[i * 19 + j] : 0.0f;
    } else if (e < OFF_WIH2BT4) {        // Wih2aT [8][256] (insulin cols 0..4)
        int q = e - OFF_WIH2AT; int j = q >> 8, i = q & 255;
        v = (j < 5) ? Wih2[i * 261 + j] : 0.0f;
    } else if (e < OFF_WHH2T4) {         // Wih2bT4 (cols 5..260)
        int q = e - OFF_WIH2BT4; int jb = q >> 10, i = (q >> 2) & 255, dj = q & 3;
        v = Wih2[i * 261 + 5 + jb * 4 + dj];
    } else if (e < OFF_OW1T4) {          // Whh2T4
        int q = e - OFF_WHH2T4; int jb = q >> 10, i = (q >> 2) & 255, dj = q & 3;
        v = Whh2[i * 256 + jb * 4 + dj];
    } else if (e < OFF_IW1T4) {          // oW1T4
        int q = e - OFF_OW1T4; int jb = q >> 10, i = (q >> 2) & 255, dj = q & 3;
        v = oW1[i * 256 + jb * 4 + dj];
    } else if (e < OFF_FW1R) {           // iW1T4
        int q = e - OFF_IW1T4; int jb = q >> 10, i = (q >> 2) & 255, dj = q & 3;
        v = iW1[i * 256 + jb * 4 + dj];
    } else if (e < OFF_FW2T4) {          // FW1R [64][256] row-major, zero-pad k>=50
        int q = e - OFF_FW1R; int k = q >> 8, j = q & 255;
        v = (k < 50) ? fW1[k * 256 + j] : 0.0f;
    } else if (e < OFF_B1C) {            // fW2T4 [13][256][4]: (kb*256+i)*4+dk = fW2[i][4kb+dk]
        int q = e - OFF_FW2T4; int kb = q >> 10, i = (q >> 2) & 255, dk = q & 3;
        int k = kb * 4 + dk;
        v = (k < 50) ? fW2[i * 50 + k] : 0.0f;
    } else if (e < OFF_B2C) {
        int q = e - OFF_B1C; v = bih1[q] + bhh1[q];
    } else {
        int q = e - OFF_B2C; v = bih2[q] + bhh2[q];
    }
    ws[e] = v;
}

// ================= main persistent kernel =================
// state numbering: s = 0: cov_b0, 1: ins_b0, 2: cov_b1, 3: ins_b1
__global__ __launch_bounds__(512, 2) void codernn_main(
    const float* __restrict__ dt, const float* __restrict__ x,
    const float* __restrict__ ws,
    const float* __restrict__ ob1, const float* __restrict__ oW2, const float* __restrict__ ob2,
    const float* __restrict__ ib1, const float* __restrict__ iW2, const float* __restrict__ ib2,
    const float* __restrict__ fb1, const float* __restrict__ fb2,
    float* __restrict__ out) {
    __shared__ float sm[L_TOTAL];
    const int tid = threadIdx.x;
    const int b = tid >> 8;          // local batch (0/1) for cell/output roles
    const int i = tid & 255;         // owned H component (cell/output roles)
    const int bg = blockIdx.x * 2 + b;
    const int lane = tid & 63, wv = tid >> 6;

    // zero h state (ycur rows, incl. pads)
    for (int idx = tid; idx < 1088; idx += 512) sm[L_YCUR + idx] = 0.0f;

    // per-thread constants (cell/output roles)
    const float b1ci = ws[OFF_B1C + i];
    const float b2ci = ws[OFF_B2C + i];
    const float ob1i = ob1[i], ib1i = ib1[i];
    const float oW2i = oW2[i], iW2i = iW2[i];
    const float ob2s = ob2[0], ib2s = ib2[0];

    // ---- z-phase role: (vg = batch, kg in 16, p16 in 16) ----
    const int vg = tid >> 8;
    const int kg = (tid >> 4) & 15;
    const int p16 = tid & 15;
    // ---- update-phase role: (v = state, ih in 128) -> comps ih, ih+128 ----
    const int v = tid >> 7;
    const int ih = tid & 127;

    const float4* Whh1T4  = (const float4*)(ws + OFF_WHH1T4);
    const float*  Wih1T   = ws + OFF_WIH1T;
    const float*  Wih2aT  = ws + OFF_WIH2AT;
    const float4* Wih2bT4 = (const float4*)(ws + OFF_WIH2BT4);
    const float4* Whh2T4  = (const float4*)(ws + OFF_WHH2T4);
    const float4* oW1T4   = (const float4*)(ws + OFF_OW1T4);
    const float4* iW1T4   = (const float4*)(ws + OFF_IW1T4);
    const float4* ycur4   = (const float4*)(sm + L_YCUR);
    const float4* hc24    = (const float4*)(sm + L_HC2);

    // ---- register-cache f-net weights ----
    // z-phase: fW1 rows 4kg..4kg+3, cols 16*p16..16*p16+15 -> wz[r][m]
    float4 wz[4][4];
    {
        const float4* g = (const float4*)(ws + OFF_FW1R);
        #pragma unroll
        for (int r = 0; r < 4; ++r)
            #pragma unroll
            for (int m = 0; m < 4; ++m)
                wz[r][m] = g[(4 * kg + r) * 64 + p16 * 4 + m];
    }
    float fb1r[4];
    #pragma unroll
    for (int r = 0; r < 4; ++r) fb1r[r] = (4 * kg + r < 50) ? fb1[4 * kg + r] : 0.0f;
    // update-phase: fW2 rows ih and ih+128 across 52 k -> 13 float4 each
    float4 wf2a[13], wf2b[13];
    {
        const float4* g = (const float4*)(ws + OFF_FW2T4);
        #pragma unroll
        for (int kb = 0; kb < 13; ++kb) {
            wf2a[kb] = g[kb * 256 + ih];
            wf2b[kb] = g[kb * 256 + ih + 128];
        }
    }
    const float fb2a = fb2[ih], fb2b = fb2[ih + 128];

    const int yA = L_YCUR + yoffF(v, ih);        // update-owned comp slots
    const int yB = L_YCUR + yoffF(v, ih + 128);
    const int ycell_c = L_YCUR + yoffF(2 * b, i);     // cell-role slots
    const int ycell_i = L_YCUR + yoffF(2 * b + 1, i);

    __syncthreads();

    for (int t = 0; t < TT; ++t) {
        // ---- stage x and treat ----
        if (tid < 56) {
            int bb = tid / 28, c = tid - bb * 28;
            sm[L_XA + tid] = (c < 25) ? x[(blockIdx.x * 2 + bb) * (TT * 25) + t * 25 + c] : 0.0f;
        }
        if (i == 0) {
            const float* xp = x + bg * (TT * 25) + t * 25;
            sm[L_TR + b] = (xp[1] > 0.f || xp[2] > 0.f || xp[3] > 0.f || xp[4] > 0.f || xp[5] > 0.f) ? 1.0f : 0.0f;
        }
        // both batches' scales (uniform loads)
        const int bg0 = blockIdx.x * 2;
        const float scale0 = (dt[bg0 * (TT * 2) + t * 2 + 1] - dt[bg0 * (TT * 2) + t * 2]) * kDT_SC;
        const float scale1 = (dt[(bg0 + 1) * (TT * 2) + t * 2 + 1] - dt[(bg0 + 1) * (TT * 2) + t * 2]) * kDT_SC;
        const float sc = (v >> 1) ? scale1 : scale0;   // update role's batch
        __syncthreads();

        // ---- cell1: h_cov += tanh(xc@Wih1' + hc@Whh1' + b) ----
        float hc_new, hi_new;
        {
            float acc = b1ci;
            acc = fmaf(Wih1T[i], sm[L_XA + b * 28 + 0], acc);
            #pragma unroll
            for (int j = 1; j < 19; ++j)
                acc = fmaf(Wih1T[j * 256 + i], sm[L_XA + b * 28 + 6 + j], acc);
            float4 a4 = {0.f, 0.f, 0.f, 0.f};
            #pragma unroll 8
            for (int jb = 0; jb < 64; ++jb) {
                float4 w = Whh1T4[jb * 256 + i];
                float4 h = ycur4[yoff4(2 * b, jb)];
                fma4(a4, w, h);
            }
            acc += rsum4(a4);
            hc_new = sm[ycell_c] + fast_tanh(acc);
            sm[L_HC2 + b * 256 + i] = hc_new;
        }
        __syncthreads();

        // ---- cell2: h_ins += tanh([xi,hc_new]@Wih2' + hi@Whh2' + b) ----
        {
            float acc = b2ci;
            #pragma unroll
            for (int j = 0; j < 5; ++j)
                acc = fmaf(Wih2aT[j * 256 + i], sm[L_XA + b * 28 + 1 + j], acc);
            float4 a4 = {0.f, 0.f, 0.f, 0.f};
            #pragma unroll 8
            for (int jb = 0; jb < 64; ++jb) {
                float4 w = Wih2bT4[jb * 256 + i];
                float4 h = hc24[b * 64 + jb];
                fma4(a4, w, h);
            }
            #pragma unroll 8
            for (int jb = 0; jb < 64; ++jb) {
                float4 w = Whh2T4[jb * 256 + i];
                float4 h = ycur4[yoff4(2 * b + 1, jb)];
                fma4(a4, w, h);
            }
            acc += rsum4(a4);
            hi_new = sm[ycell_i] + fast_tanh(acc);
        }
        __syncthreads();
        // publish post-cell states
        sm[ycell_c] = hc_new;
        sm[ycell_i] = hi_new;
        __syncthreads();

        // ODE base state for owned comps
        float y0a = sm[yA], y0b = sm[yB];

        // ---- ODE: 8 RK4 steps, 4 state vectors simultaneously ----
        for (int st = 0; st < NSTEP; ++st) {
            float acca = 0.f, accb = 0.f;
            #pragma unroll
            for (int e = 0; e < 4; ++e) {
                if (e > 0) __syncthreads();   // ycur ready (e==0 covered above)
                // z-phase: 4-row x 16-col fW1 tile, both states of batch vg
                float pz[8];
                #pragma unroll
                for (int s = 0; s < 2; ++s) {
                    const float4* ys = ycur4 + (2 * vg + s) * 68 + (p16 >> 2) * 17 + (p16 & 3) * 4;
                    float4 P0 = {0,0,0,0}, P1 = {0,0,0,0}, P2 = {0,0,0,0}, P3 = {0,0,0,0};
                    #pragma unroll
                    for (int m = 0; m < 4; ++m) {
                        float4 y = ys[m];
                        fma4(P0, wz[0][m], y);
                        fma4(P1, wz[1][m], y);
                        fma4(P2, wz[2][m], y);
                        fma4(P3, wz[3][m], y);
                    }
                    pz[s * 4 + 0] = rsum4(P0); pz[s * 4 + 1] = rsum4(P1);
                    pz[s * 4 + 2] = rsum4(P2); pz[s * 4 + 3] = rsum4(P3);
                }
                #pragma unroll
                for (int r = 0; r < 8; ++r) {
                    pz[r] += __shfl_xor(pz[r], 1);
                    pz[r] += __shfl_xor(pz[r], 2);
                    pz[r] += __shfl_xor(pz[r], 4);
                    pz[r] += __shfl_xor(pz[r], 8);
                }
                if (p16 < 8) {
                    const int q = p16;
                    float a0 = (q & 1) ? pz[1] : pz[0];
                    float a1 = (q & 1) ? pz[3] : pz[2];
                    float a2 = (q & 1) ? pz[5] : pz[4];
                    float a3 = (q & 1) ? pz[7] : pz[6];
                    float b0s = (q & 2) ? a1 : a0;
                    float b1s = (q & 2) ? a3 : a2;
                    float vsum = (q & 4) ? b1s : b0s;
                    float f0 = (q & 1) ? fb1r[1] : fb1r[0];
                    float f1 = (q & 1) ? fb1r[3] : fb1r[2];
                    float fb = (q & 2) ? f1 : f0;
                    sm[L_Z + (2 * vg + (q >> 2)) * 64 + 4 * kg + (q & 3)] = fast_tanh(vsum + fb);
                }
                __syncthreads();   // z ready
                // update: du = (fW2.z + fb2) * sc for comps (v, ih) and (v, ih+128)
                {
                    const float4* zv = (const float4*)(sm + L_Z + v * 64);
                    float4 A = {0,0,0,0}, Bq = {0,0,0,0};
                    #pragma unroll
                    for (int kb = 0; kb < 13; ++kb) {
                        float4 z = zv[kb];
                        fma4(A, wf2a[kb], z);
                        fma4(Bq, wf2b[kb], z);
                    }
                    float dua = (fb2a + rsum4(A)) * sc;
                    float dub = (fb2b + rsum4(Bq)) * sc;
                    float ya, yb;
                    if (e == 0) {
                        acca = dua; accb = dub;
                        ya = fmaf(0.5f * HS, dua, y0a); yb = fmaf(0.5f * HS, dub, y0b);
                    } else if (e == 1) {
                        acca = fmaf(2.f, dua, acca); accb = fmaf(2.f, dub, accb);
                        ya = fmaf(0.5f * HS, dua, y0a); yb = fmaf(0.5f * HS, dub, y0b);
                    } else if (e == 2) {
                        acca = fmaf(2.f, dua, acca); accb = fmaf(2.f, dub, accb);
                        ya = fmaf(HS, dua, y0a); yb = fmaf(HS, dub, y0b);
                    } else {
                        acca += dua; accb += dub;
                        y0a = fmaf(HS / 6.f, acca, y0a); y0b = fmaf(HS / 6.f, accb, y0b);
                        ya = y0a; yb = y0b;
                    }
                    sm[yA] = ya;
                    sm[yB] = yb;
                }
            }
        }
        __syncthreads();   // final ycur (== h) visible

        // ---- output heads + reduction ----
        {
            float4 ao4 = {0.f,0.f,0.f,0.f}, ai4 = {0.f,0.f,0.f,0.f};
            #pragma unroll 8
            for (int jb = 0; jb < 64; ++jb) {
                float4 wo = oW1T4[jb * 256 + i];
                float4 hcv = ycur4[yoff4(2 * b, jb)];
                fma4(ao4, wo, hcv);
                float4 wi = iW1T4[jb * 256 + i];
                float4 hiv = ycur4[yoff4(2 * b + 1, jb)];
                fma4(ai4, wi, hiv);
            }
            float co = oW2i * fast_tanh(ob1i + rsum4(ao4));
            float ci = iW2i * fast_tanh(ib1i + rsum4(ai4));
            #pragma unroll
            for (int off = 32; off > 0; off >>= 1) {
                co += __shfl_xor(co, off);
                ci += __shfl_xor(ci, off);
            }
            if (lane == 0) { sm[L_RED + wv * 2] = co; sm[L_RED + wv * 2 + 1] = ci; }
        }
        __syncthreads();
        if (i == 0) {
            float sco = sm[L_RED + b * 8 + 0] + sm[L_RED + b * 8 + 2] + sm[L_RED + b * 8 + 4] + sm[L_RED + b * 8 + 6];
            float sci = sm[L_RED + b * 8 + 1] + sm[L_RED + b * 8 + 3] + sm[L_RED + b * 8 + 5] + sm[L_RED + b * 8 + 7];
            float muc = sco + ob2s;
            float mui = fmaxf(sci + ib2s, 0.0f);
            out[bg * TT + t] = muc - sm[L_TR + b] * mui;
        }
        __syncthreads();
    }
}

extern "C" void kernel_launch(void* const* d_in, const int* in_sizes, int n_in,
                              void* d_out, int out_size, void* d_ws, size_t ws_size,
                              hipStream_t stream) {
    const float* dt   = (const float*)d_in[0];
    const float* x    = (const float*)d_in[1];
    const float* Wih1 = (const float*)d_in[2];
    const float* Whh1 = (const float*)d_in[3];
    const float* bih1 = (const float*)d_in[4];
    const float* bhh1 = (const float*)d_in[5];
    const float* Wih2 = (const float*)d_in[6];
    const float* Whh2 = (const float*)d_in[7];
    const float* bih2 = (const float*)d_in[8];
    const float* bhh2 = (const float*)d_in[9];
    const float* oW1  = (const float*)d_in[10];
    const float* ob1  = (const float*)d_in[11];
    const float* oW2  = (const float*)d_in[12];
    const float* ob2  = (const float*)d_in[13];
    const float* iW1  = (const float*)d_in[14];
    const float* ib1  = (const float*)d_in[15];
    const float* iW2  = (const float*)d_in[16];
    const float* ib2  = (const float*)d_in[17];
    const float* fW1  = (const float*)d_in[18];
    const float* fb1  = (const float*)d_in[19];
    const float* fW2  = (const float*)d_in[20];
    const float* fb2  = (const float*)d_in[21];
    float* ws  = (float*)d_ws;
    float* out = (float*)d_out;

    if (ws_size < (size_t)WS_FLOATS * sizeof(float)) return;  // need ~1.46 MB scratch

    codernn_setup<<<WS_FLOATS / 256, 256, 0, stream>>>(Wih1, Whh1, bih1, bhh1, Wih2, Whh2,
                                                       bih2, bhh2, oW1, iW1, fW1, fW2, ws);

    codernn_main<<<256, 512, 0, stream>>>(dt, x, ws,
                                          ob1, oW2, ob2, ib1, iW2, ib2, fb1, fb2, out);
}

// Round 4
// 11987.049 us; speedup vs baseline: 1.1428x; 1.1428x over previous
//
#include <hip/hip_runtime.h>

// ---------------- problem constants ----------------
#define TT 100
#define HH 256
#define NSTEP 8
__device__ __constant__ float kDT_SC = 1.0f / 24.0f;
#define HS (0.125f)          // 1/NSTEP

// ---------------- d_ws layout (floats) ----------------
#define OFF_WHH1T4   0         // [64][256][4]
#define OFF_WIH1T    65536     // [20][256]
#define OFF_WIH2AT   70656     // [8][256]
#define OFF_WIH2BT4  72704     // [64][256][4]
#define OFF_WHH2T4   138240    // [64][256][4]
#define OFF_OW1T4    203776    // [64][256][4]
#define OFF_IW1T4    269312    // [64][256][4]
#define OFF_FW1R     334848    // [64][256] row-major, zero-padded rows >= 50
#define OFF_FW2T4    351232    // [13][256][4]
#define OFF_B1C      364544    // [256] bih1+bhh1
#define OFF_B2C      364800    // [256] bih2+bhh2
#define WS_FLOATS    365056

// ---------------- LDS layout (floats) ----------------
#define L_YCUR  0        // 4 rows * 272 (4 chunks of 68 = 64 data + 4 pad)
#define L_Z     1088     // 4 states * 64
#define L_HC2   1344     // 2 * 256
#define L_XA    1856     // 2 * 28
#define L_TR    1912     // 2
#define L_RED   1914     // 16
#define L_TOTAL 1930

__device__ __forceinline__ float fast_tanh(float v) {
    float e = __expf(2.0f * v);
    return 1.0f - 2.0f / (e + 1.0f);
}
__device__ __forceinline__ void fma4(float4& a, const float4 w, const float4 h) {
    a.x = fmaf(w.x, h.x, a.x); a.y = fmaf(w.y, h.y, a.y);
    a.z = fmaf(w.z, h.z, a.z); a.w = fmaf(w.w, h.w, a.w);
}
__device__ __forceinline__ float rsum4(const float4 a) { return (a.x + a.y) + (a.z + a.w); }
// padded ycur indexing: row v has 4 chunks of 68 floats (64 valid + 4 pad)
__device__ __forceinline__ int yoffF(int v, int j) { return v * 272 + (j >> 6) * 68 + (j & 63); }
__device__ __forceinline__ int yoff4(int v, int jb) { return v * 68 + (jb >> 4) * 17 + (jb & 15); }

// 16-lane allreduce via DPP rotate-add (row_ror:1,2,4,8) — pure VALU, no LDS pipe
template <int CTRL>
__device__ __forceinline__ float dpp_rr_add(float v) {
    int r = __builtin_amdgcn_update_dpp(0, __float_as_int(v), CTRL, 0xF, 0xF, false);
    return v + __int_as_float(r);
}
__device__ __forceinline__ float allreduce16(float v) {
    v = dpp_rr_add<0x121>(v);   // row_ror:1
    v = dpp_rr_add<0x122>(v);   // row_ror:2
    v = dpp_rr_add<0x124>(v);   // row_ror:4
    v = dpp_rr_add<0x128>(v);   // row_ror:8
    return v;
}

// ================= setup: repack weights into d_ws =================
__global__ void codernn_setup(const float* __restrict__ Wih1, const float* __restrict__ Whh1,
                              const float* __restrict__ bih1, const float* __restrict__ bhh1,
                              const float* __restrict__ Wih2, const float* __restrict__ Whh2,
                              const float* __restrict__ bih2, const float* __restrict__ bhh2,
                              const float* __restrict__ oW1, const float* __restrict__ iW1,
                              const float* __restrict__ fW1, const float* __restrict__ fW2,
                              float* __restrict__ ws) {
    int e = blockIdx.x * 256 + threadIdx.x;
    if (e >= WS_FLOATS) return;
    float v;
    if (e < OFF_WIH1T) {                 // Whh1T4
        int q = e; int jb = q >> 10, i = (q >> 2) & 255, dj = q & 3;
        v = Whh1[i * 256 + jb * 4 + dj];
    } else if (e < OFF_WIH2AT) {         // Wih1T [20][256]
        int q = e - OFF_WIH1T; int j = q >> 8, i = q & 255;
        v = (j < 19) ? Wih1[i * 19 + j] : 0.0f;
    } else if (e < OFF_WIH2BT4) {        // Wih2aT [8][256] (insulin cols 0..4)
        int q = e - OFF_WIH2AT; int j = q >> 8, i = q & 255;
        v = (j < 5) ? Wih2[i * 261 + j] : 0.0f;
    } else if (e < OFF_WHH2T4) {         // Wih2bT4 (cols 5..260)
        int q = e - OFF_WIH2BT4; int jb = q >> 10, i = (q >> 2) & 255, dj = q & 3;
        v = Wih2[i * 261 + 5 + jb * 4 + dj];
    } else if (e < OFF_OW1T4) {          // Whh2T4
        int q = e - OFF_WHH2T4; int jb = q >> 10, i = (q >> 2) & 255, dj = q & 3;
        v = Whh2[i * 256 + jb * 4 + dj];
    } else if (e < OFF_IW1T4) {          // oW1T4
        int q = e - OFF_OW1T4; int jb = q >> 10, i = (q >> 2) & 255, dj = q & 3;
        v = oW1[i * 256 + jb * 4 + dj];
    } else if (e < OFF_FW1R) {           // iW1T4
        int q = e - OFF_IW1T4; int jb = q >> 10, i = (q >> 2) & 255, dj = q & 3;
        v = iW1[i * 256 + jb * 4 + dj];
    } else if (e < OFF_FW2T4) {          // FW1R [64][256] row-major, zero-pad k>=50
        int q = e - OFF_FW1R; int k = q >> 8, j = q & 255;
        v = (k < 50) ? fW1[k * 256 + j] : 0.0f;
    } else if (e < OFF_B1C) {            // fW2T4 [13][256][4]: (kb*256+i)*4+dk = fW2[i][4kb+dk]
        int q = e - OFF_FW2T4; int kb = q >> 10, i = (q >> 2) & 255, dk = q & 3;
        int k = kb * 4 + dk;
        v = (k < 50) ? fW2[i * 50 + k] : 0.0f;
    } else if (e < OFF_B2C) {
        int q = e - OFF_B1C; v = bih1[q] + bhh1[q];
    } else {
        int q = e - OFF_B2C; v = bih2[q] + bhh2[q];
    }
    ws[e] = v;
}

// ================= main persistent kernel =================
// state numbering: s = 0: cov_b0, 1: ins_b0, 2: cov_b1, 3: ins_b1
__global__ __launch_bounds__(512) __attribute__((amdgpu_waves_per_eu(2, 2)))
void codernn_main(
    const float* __restrict__ dt, const float* __restrict__ x,
    const float* __restrict__ ws,
    const float* __restrict__ ob1, const float* __restrict__ oW2, const float* __restrict__ ob2,
    const float* __restrict__ ib1, const float* __restrict__ iW2, const float* __restrict__ ib2,
    const float* __restrict__ fb1, const float* __restrict__ fb2,
    float* __restrict__ out) {
    __shared__ float sm[L_TOTAL];
    const int tid = threadIdx.x;
    const int b = tid >> 8;          // local batch (0/1) for cell/output roles
    const int i = tid & 255;         // owned H component (cell/output roles)
    const int bg = blockIdx.x * 2 + b;
    const int lane = tid & 63, wv = tid >> 6;

    // zero h state (ycur rows, incl. pads)
    for (int idx = tid; idx < 1088; idx += 512) sm[L_YCUR + idx] = 0.0f;

    // per-thread constants (cell/output roles)
    const float b1ci = ws[OFF_B1C + i];
    const float b2ci = ws[OFF_B2C + i];
    const float ob1i = ob1[i], ib1i = ib1[i];
    const float oW2i = oW2[i], iW2i = iW2[i];
    const float ob2s = ob2[0], ib2s = ib2[0];

    // ---- z-phase role: (vg = batch, kg in 16, p16 in 16) ----
    const int vg = tid >> 8;
    const int kg = (tid >> 4) & 15;
    const int p16 = tid & 15;
    // ---- update-phase role: (v = state, ih in 128) -> comps ih, ih+128 ----
    const int v = tid >> 7;
    const int ih = tid & 127;

    const float4* Whh1T4  = (const float4*)(ws + OFF_WHH1T4);
    const float*  Wih1T   = ws + OFF_WIH1T;
    const float*  Wih2aT  = ws + OFF_WIH2AT;
    const float4* Wih2bT4 = (const float4*)(ws + OFF_WIH2BT4);
    const float4* Whh2T4  = (const float4*)(ws + OFF_WHH2T4);
    const float4* oW1T4   = (const float4*)(ws + OFF_OW1T4);
    const float4* iW1T4   = (const float4*)(ws + OFF_IW1T4);
    const float4* ycur4   = (const float4*)(sm + L_YCUR);
    const float4* hc24    = (const float4*)(sm + L_HC2);

    // ---- register-cache f-net weights ----
    // z-phase: fW1 rows 4kg..4kg+3, cols 16*p16..16*p16+15 -> wz[r][m]
    float4 wz[4][4];
    {
        const float4* g = (const float4*)(ws + OFF_FW1R);
        #pragma unroll
        for (int r = 0; r < 4; ++r)
            #pragma unroll
            for (int m = 0; m < 4; ++m)
                wz[r][m] = g[(4 * kg + r) * 64 + p16 * 4 + m];
    }
    float fb1r[4];
    #pragma unroll
    for (int r = 0; r < 4; ++r) fb1r[r] = (4 * kg + r < 50) ? fb1[4 * kg + r] : 0.0f;
    // update-phase: fW2 rows ih and ih+128 across 52 k -> 13 float4 each
    float4 wf2a[13], wf2b[13];
    {
        const float4* g = (const float4*)(ws + OFF_FW2T4);
        #pragma unroll
        for (int kb = 0; kb < 13; ++kb) {
            wf2a[kb] = g[kb * 256 + ih];
            wf2b[kb] = g[kb * 256 + ih + 128];
        }
    }
    const float fb2a = fb2[ih], fb2b = fb2[ih + 128];

    const int yA = L_YCUR + yoffF(v, ih);        // update-owned comp slots
    const int yB = L_YCUR + yoffF(v, ih + 128);
    const int ycell_c = L_YCUR + yoffF(2 * b, i);     // cell-role slots
    const int ycell_i = L_YCUR + yoffF(2 * b + 1, i);

    __syncthreads();

    for (int t = 0; t < TT; ++t) {
        // ---- stage x and treat ----
        if (tid < 56) {
            int bb = tid / 28, c = tid - bb * 28;
            sm[L_XA + tid] = (c < 25) ? x[(blockIdx.x * 2 + bb) * (TT * 25) + t * 25 + c] : 0.0f;
        }
        if (i == 0) {
            const float* xp = x + bg * (TT * 25) + t * 25;
            sm[L_TR + b] = (xp[1] > 0.f || xp[2] > 0.f || xp[3] > 0.f || xp[4] > 0.f || xp[5] > 0.f) ? 1.0f : 0.0f;
        }
        // both batches' scales (uniform loads)
        const int bg0 = blockIdx.x * 2;
        const float scale0 = (dt[bg0 * (TT * 2) + t * 2 + 1] - dt[bg0 * (TT * 2) + t * 2]) * kDT_SC;
        const float scale1 = (dt[(bg0 + 1) * (TT * 2) + t * 2 + 1] - dt[(bg0 + 1) * (TT * 2) + t * 2]) * kDT_SC;
        const float sc = (v >> 1) ? scale1 : scale0;   // update role's batch
        __syncthreads();

        // ---- cell1: h_cov += tanh(xc@Wih1' + hc@Whh1' + b) ----
        float hc_new, hi_new;
        {
            float acc = b1ci;
            acc = fmaf(Wih1T[i], sm[L_XA + b * 28 + 0], acc);
            #pragma unroll
            for (int j = 1; j < 19; ++j)
                acc = fmaf(Wih1T[j * 256 + i], sm[L_XA + b * 28 + 6 + j], acc);
            float4 a4 = {0.f, 0.f, 0.f, 0.f};
            #pragma unroll 4
            for (int jb = 0; jb < 64; ++jb) {
                float4 w = Whh1T4[jb * 256 + i];
                float4 h = ycur4[yoff4(2 * b, jb)];
                fma4(a4, w, h);
            }
            acc += rsum4(a4);
            hc_new = sm[ycell_c] + fast_tanh(acc);
            sm[L_HC2 + b * 256 + i] = hc_new;
        }
        __syncthreads();

        // ---- cell2: h_ins += tanh([xi,hc_new]@Wih2' + hi@Whh2' + b) ----
        {
            float acc = b2ci;
            #pragma unroll
            for (int j = 0; j < 5; ++j)
                acc = fmaf(Wih2aT[j * 256 + i], sm[L_XA + b * 28 + 1 + j], acc);
            float4 a4 = {0.f, 0.f, 0.f, 0.f};
            #pragma unroll 4
            for (int jb = 0; jb < 64; ++jb) {
                float4 w = Wih2bT4[jb * 256 + i];
                float4 h = hc24[b * 64 + jb];
                fma4(a4, w, h);
            }
            #pragma unroll 4
            for (int jb = 0; jb < 64; ++jb) {
                float4 w = Whh2T4[jb * 256 + i];
                float4 h = ycur4[yoff4(2 * b + 1, jb)];
                fma4(a4, w, h);
            }
            acc += rsum4(a4);
            hi_new = sm[ycell_i] + fast_tanh(acc);
        }
        __syncthreads();
        // publish post-cell states
        sm[ycell_c] = hc_new;
        sm[ycell_i] = hi_new;
        __syncthreads();

        // ODE base state for owned comps
        float y0a = sm[yA], y0b = sm[yB];

        // ---- ODE: 8 RK4 steps, 4 state vectors simultaneously ----
        for (int st = 0; st < NSTEP; ++st) {
            float acca = 0.f, accb = 0.f;
            #pragma unroll
            for (int e = 0; e < 4; ++e) {
                __syncthreads();   // ycur writes (prev stage / init) visible
                // z-phase: 4-row x 16-col fW1 tile, both states of batch vg
                float pz[8];
                #pragma unroll
                for (int s = 0; s < 2; ++s) {
                    const float4* ys = ycur4 + (2 * vg + s) * 68 + (p16 >> 2) * 17 + (p16 & 3) * 4;
                    float4 P0 = {0,0,0,0}, P1 = {0,0,0,0}, P2 = {0,0,0,0}, P3 = {0,0,0,0};
                    #pragma unroll
                    for (int m = 0; m < 4; ++m) {
                        float4 y = ys[m];
                        fma4(P0, wz[0][m], y);
                        fma4(P1, wz[1][m], y);
                        fma4(P2, wz[2][m], y);
                        fma4(P3, wz[3][m], y);
                    }
                    pz[s * 4 + 0] = rsum4(P0); pz[s * 4 + 1] = rsum4(P1);
                    pz[s * 4 + 2] = rsum4(P2); pz[s * 4 + 3] = rsum4(P3);
                }
                #pragma unroll
                for (int r = 0; r < 8; ++r) pz[r] = allreduce16(pz[r]);
                if (p16 < 8) {
                    const int q = p16;
                    float a0 = (q & 1) ? pz[1] : pz[0];
                    float a1 = (q & 1) ? pz[3] : pz[2];
                    float a2 = (q & 1) ? pz[5] : pz[4];
                    float a3 = (q & 1) ? pz[7] : pz[6];
                    float b0s = (q & 2) ? a1 : a0;
                    float b1s = (q & 2) ? a3 : a2;
                    float vsum = (q & 4) ? b1s : b0s;
                    float f0 = (q & 1) ? fb1r[1] : fb1r[0];
                    float f1 = (q & 1) ? fb1r[3] : fb1r[2];
                    float fb = (q & 2) ? f1 : f0;
                    sm[L_Z + (2 * vg + (q >> 2)) * 64 + 4 * kg + (q & 3)] = fast_tanh(vsum + fb);
                }
                __syncthreads();   // z ready
                // update: du = (fW2.z + fb2) * sc for comps (v, ih) and (v, ih+128)
                {
                    const float4* zv = (const float4*)(sm + L_Z + v * 64);
                    float4 A = {0,0,0,0}, Bq = {0,0,0,0};
                    #pragma unroll
                    for (int kb = 0; kb < 13; ++kb) {
                        float4 z = zv[kb];
                        fma4(A, wf2a[kb], z);
                        fma4(Bq, wf2b[kb], z);
                    }
                    float dua = (fb2a + rsum4(A)) * sc;
                    float dub = (fb2b + rsum4(Bq)) * sc;
                    float ya, yb;
                    if (e == 0) {
                        acca = dua; accb = dub;
                        ya = fmaf(0.5f * HS, dua, y0a); yb = fmaf(0.5f * HS, dub, y0b);
                    } else if (e == 1) {
                        acca = fmaf(2.f, dua, acca); accb = fmaf(2.f, dub, accb);
                        ya = fmaf(0.5f * HS, dua, y0a); yb = fmaf(0.5f * HS, dub, y0b);
                    } else if (e == 2) {
                        acca = fmaf(2.f, dua, acca); accb = fmaf(2.f, dub, accb);
                        ya = fmaf(HS, dua, y0a); yb = fmaf(HS, dub, y0b);
                    } else {
                        acca += dua; accb += dub;
                        y0a = fmaf(HS / 6.f, acca, y0a); y0b = fmaf(HS / 6.f, accb, y0b);
                        ya = y0a; yb = y0b;
                    }
                    sm[yA] = ya;
                    sm[yB] = yb;
                }
            }
        }
        __syncthreads();   // final ycur (== h) visible

        // ---- output heads + reduction ----
        {
            float4 ao4 = {0.f,0.f,0.f,0.f}, ai4 = {0.f,0.f,0.f,0.f};
            #pragma unroll 4
            for (int jb = 0; jb < 64; ++jb) {
                float4 wo = oW1T4[jb * 256 + i];
                float4 hcv = ycur4[yoff4(2 * b, jb)];
                fma4(ao4, wo, hcv);
                float4 wi = iW1T4[jb * 256 + i];
                float4 hiv = ycur4[yoff4(2 * b + 1, jb)];
                fma4(ai4, wi, hiv);
            }
            float co = oW2i * fast_tanh(ob1i + rsum4(ao4));
            float ci = iW2i * fast_tanh(ib1i + rsum4(ai4));
            #pragma unroll
            for (int off = 32; off > 0; off >>= 1) {
                co += __shfl_xor(co, off);
                ci += __shfl_xor(ci, off);
            }
            if (lane == 0) { sm[L_RED + wv * 2] = co; sm[L_RED + wv * 2 + 1] = ci; }
        }
        __syncthreads();
        if (i == 0) {
            float sco = sm[L_RED + b * 8 + 0] + sm[L_RED + b * 8 + 2] + sm[L_RED + b * 8 + 4] + sm[L_RED + b * 8 + 6];
            float sci = sm[L_RED + b * 8 + 1] + sm[L_RED + b * 8 + 3] + sm[L_RED + b * 8 + 5] + sm[L_RED + b * 8 + 7];
            float muc = sco + ob2s;
            float mui = fmaxf(sci + ib2s, 0.0f);
            out[bg * TT + t] = muc - sm[L_TR + b] * mui;
        }
        __syncthreads();
    }
}

extern "C" void kernel_launch(void* const* d_in, const int* in_sizes, int n_in,
                              void* d_out, int out_size, void* d_ws, size_t ws_size,
                              hipStream_t stream) {
    const float* dt   = (const float*)d_in[0];
    const float* x    = (const float*)d_in[1];
    const float* Wih1 = (const float*)d_in[2];
    const float* Whh1 = (const float*)d_in[3];
    const float* bih1 = (const float*)d_in[4];
    const float* bhh1 = (const float*)d_in[5];
    const float* Wih2 = (const float*)d_in[6];
    const float* Whh2 = (const float*)d_in[7];
    const float* bih2 = (const float*)d_in[8];
    const float* bhh2 = (const float*)d_in[9];
    const float* oW1  = (const float*)d_in[10];
    const float* ob1  = (const float*)d_in[11];
    const float* oW2  = (const float*)d_in[12];
    const float* ob2  = (const float*)d_in[13];
    const float* iW1  = (const float*)d_in[14];
    const float* ib1  = (const float*)d_in[15];
    const float* iW2  = (const float*)d_in[16];
    const float* ib2  = (const float*)d_in[17];
    const float* fW1  = (const float*)d_in[18];
    const float* fb1  = (const float*)d_in[19];
    const float* fW2  = (const float*)d_in[20];
    const float* fb2  = (const float*)d_in[21];
    float* ws  = (float*)d_ws;
    float* out = (float*)d_out;

    if (ws_size < (size_t)WS_FLOATS * sizeof(float)) return;  // need ~1.46 MB scratch

    codernn_setup<<<WS_FLOATS / 256, 256, 0, stream>>>(Wih1, Whh1, bih1, bhh1, Wih2, Whh2,
                                                       bih2, bhh2, oW1, iW1, fW1, fW2, ws);

    codernn_main<<<256, 512, 0, stream>>>(dt, x, ws,
                                          ob1, oW2, ob2, ib1, iW2, ib2, fb1, fb2, out);
}

// Round 5
// 6603.734 us; speedup vs baseline: 2.0745x; 1.8152x over previous
//
#include <hip/hip_runtime.h>

// ---------------- problem constants ----------------
#define TT 100
#define HH 256
#define NSTEP 8
__device__ __constant__ float kDT_SC = 1.0f / 24.0f;
#define HS (0.125f)          // 1/NSTEP

// ---------------- d_ws layout (floats) ----------------
#define OFF_WHH1T4   0         // [64][256][4]
#define OFF_WIH1T    65536     // [20][256]
#define OFF_WIH2AT   70656     // [8][256]
#define OFF_WIH2BT4  72704     // [64][256][4]
#define OFF_WHH2T4   138240    // [64][256][4]
#define OFF_OW1T4    203776    // [64][256][4]
#define OFF_IW1T4    269312    // [64][256][4]
#define OFF_FW1R     334848    // [64][256] row-major, zero-padded rows >= 50
#define OFF_FW2T4    351232    // [13][256][4]
#define OFF_B1C      364544    // [256] bih1+bhh1
#define OFF_B2C      364800    // [256] bih2+bhh2
#define WS_FLOATS    365056

// ---------------- LDS layout (floats) ----------------
#define L_FW2   0        // [13][256][4] staged fW2T4 = 13312
#define L_YCUR  13312    // 4 rows * 272 (4 chunks of 68 = 64 data + 4 pad)
#define L_Z     14400    // 4 states * 64
#define L_HC2   14656    // 2 * 256
#define L_XA    15168    // 2 * 28
#define L_TR    15224    // 2
#define L_RED   15226    // 16
#define L_TOTAL 15242

__device__ __forceinline__ float fast_tanh(float v) {
    float e = __expf(2.0f * v);
    return 1.0f - 2.0f / (e + 1.0f);
}
__device__ __forceinline__ void fma4(float4& a, const float4 w, const float4 h) {
    a.x = fmaf(w.x, h.x, a.x); a.y = fmaf(w.y, h.y, a.y);
    a.z = fmaf(w.z, h.z, a.z); a.w = fmaf(w.w, h.w, a.w);
}
__device__ __forceinline__ float rsum4(const float4 a) { return (a.x + a.y) + (a.z + a.w); }
// padded ycur indexing: row v has 4 chunks of 68 floats (64 valid + 4 pad)
__device__ __forceinline__ int yoffF(int v, int j) { return v * 272 + (j >> 6) * 68 + (j & 63); }
__device__ __forceinline__ int yoff4(int v, int jb) { return v * 68 + (jb >> 4) * 17 + (jb & 15); }

// 16-lane allreduce via DPP rotate-add (row_ror:1,2,4,8) — pure VALU, no LDS pipe
template <int CTRL>
__device__ __forceinline__ float dpp_rr_add(float v) {
    int r = __builtin_amdgcn_update_dpp(0, __float_as_int(v), CTRL, 0xF, 0xF, false);
    return v + __int_as_float(r);
}
__device__ __forceinline__ float allreduce16(float v) {
    v = dpp_rr_add<0x121>(v);   // row_ror:1
    v = dpp_rr_add<0x122>(v);   // row_ror:2
    v = dpp_rr_add<0x124>(v);   // row_ror:4
    v = dpp_rr_add<0x128>(v);   // row_ror:8
    return v;
}

// ================= setup: repack weights into d_ws =================
__global__ void codernn_setup(const float* __restrict__ Wih1, const float* __restrict__ Whh1,
                              const float* __restrict__ bih1, const float* __restrict__ bhh1,
                              const float* __restrict__ Wih2, const float* __restrict__ Whh2,
                              const float* __restrict__ bih2, const float* __restrict__ bhh2,
                              const float* __restrict__ oW1, const float* __restrict__ iW1,
                              const float* __restrict__ fW1, const float* __restrict__ fW2,
                              float* __restrict__ ws) {
    int e = blockIdx.x * 256 + threadIdx.x;
    if (e >= WS_FLOATS) return;
    float v;
    if (e < OFF_WIH1T) {                 // Whh1T4
        int q = e; int jb = q >> 10, i = (q >> 2) & 255, dj = q & 3;
        v = Whh1[i * 256 + jb * 4 + dj];
    } else if (e < OFF_WIH2AT) {         // Wih1T [20][256]
        int q = e - OFF_WIH1T; int j = q >> 8, i = q & 255;
        v = (j < 19) ? Wih1[i * 19 + j] : 0.0f;
    } else if (e < OFF_WIH2BT4) {        // Wih2aT [8][256] (insulin cols 0..4)
        int q = e - OFF_WIH2AT; int j = q >> 8, i = q & 255;
        v = (j < 5) ? Wih2[i * 261 + j] : 0.0f;
    } else if (e < OFF_WHH2T4) {         // Wih2bT4 (cols 5..260)
        int q = e - OFF_WIH2BT4; int jb = q >> 10, i = (q >> 2) & 255, dj = q & 3;
        v = Wih2[i * 261 + 5 + jb * 4 + dj];
    } else if (e < OFF_OW1T4) {          // Whh2T4
        int q = e - OFF_WHH2T4; int jb = q >> 10, i = (q >> 2) & 255, dj = q & 3;
        v = Whh2[i * 256 + jb * 4 + dj];
    } else if (e < OFF_IW1T4) {          // oW1T4
        int q = e - OFF_OW1T4; int jb = q >> 10, i = (q >> 2) & 255, dj = q & 3;
        v = oW1[i * 256 + jb * 4 + dj];
    } else if (e < OFF_FW1R) {           // iW1T4
        int q = e - OFF_IW1T4; int jb = q >> 10, i = (q >> 2) & 255, dj = q & 3;
        v = iW1[i * 256 + jb * 4 + dj];
    } else if (e < OFF_FW2T4) {          // FW1R [64][256] row-major, zero-pad k>=50
        int q = e - OFF_FW1R; int k = q >> 8, j = q & 255;
        v = (k < 50) ? fW1[k * 256 + j] : 0.0f;
    } else if (e < OFF_B1C) {            // fW2T4 [13][256][4]: (kb*256+i)*4+dk = fW2[i][4kb+dk]
        int q = e - OFF_FW2T4; int kb = q >> 10, i = (q >> 2) & 255, dk = q & 3;
        int k = kb * 4 + dk;
        v = (k < 50) ? fW2[i * 50 + k] : 0.0f;
    } else if (e < OFF_B2C) {
        int q = e - OFF_B1C; v = bih1[q] + bhh1[q];
    } else {
        int q = e - OFF_B2C; v = bih2[q] + bhh2[q];
    }
    ws[e] = v;
}

// ================= main persistent kernel =================
// state numbering: s = 0: cov_b0, 1: ins_b0, 2: cov_b1, 3: ins_b1
__global__ __launch_bounds__(512, 2) void codernn_main(
    const float* __restrict__ dt, const float* __restrict__ x,
    const float* __restrict__ ws,
    const float* __restrict__ ob1, const float* __restrict__ oW2, const float* __restrict__ ob2,
    const float* __restrict__ ib1, const float* __restrict__ iW2, const float* __restrict__ ib2,
    const float* __restrict__ fb1, const float* __restrict__ fb2,
    float* __restrict__ out) {
    __shared__ float sm[L_TOTAL];
    const int tid = threadIdx.x;
    const int b = tid >> 8;          // batch (0/1): cell + update + output roles
    const int i = tid & 255;         // owned H component
    const int bg = blockIdx.x * 2 + b;
    const int lane = tid & 63, wv = tid >> 6;

    // stage fW2T4 into LDS; zero h state (ycur rows, incl. pads)
    for (int idx = tid; idx < 13312; idx += 512) sm[L_FW2 + idx] = ws[OFF_FW2T4 + idx];
    for (int idx = tid; idx < 1088; idx += 512) sm[L_YCUR + idx] = 0.0f;

    // per-thread constants
    const float b1ci = ws[OFF_B1C + i];
    const float b2ci = ws[OFF_B2C + i];
    const float ob1i = ob1[i], ib1i = ib1[i];
    const float oW2i = oW2[i], iW2i = iW2[i];
    const float fb2i = fb2[i];
    const float ob2s = ob2[0], ib2s = ib2[0];

    // ---- z-phase role: (vg = batch, kg in 16, p16 in 16) ----
    const int vg = tid >> 8;
    const int kg = (tid >> 4) & 15;
    const int p16 = tid & 15;

    const float4* Whh1T4  = (const float4*)(ws + OFF_WHH1T4);
    const float*  Wih1T   = ws + OFF_WIH1T;
    const float*  Wih2aT  = ws + OFF_WIH2AT;
    const float4* Wih2bT4 = (const float4*)(ws + OFF_WIH2BT4);
    const float4* Whh2T4  = (const float4*)(ws + OFF_WHH2T4);
    const float4* oW1T4   = (const float4*)(ws + OFF_OW1T4);
    const float4* iW1T4   = (const float4*)(ws + OFF_IW1T4);
    const float4* ycur4   = (const float4*)(sm + L_YCUR);
    const float4* hc24    = (const float4*)(sm + L_HC2);
    const float4* fw2l    = (const float4*)(sm + L_FW2);

    // ---- register-cache fW1 only (64 VGPR): rows 4kg..4kg+3, cols 16*p16..+15
    float4 wz[4][4];
    {
        const float4* g = (const float4*)(ws + OFF_FW1R);
        #pragma unroll
        for (int r = 0; r < 4; ++r)
            #pragma unroll
            for (int m = 0; m < 4; ++m)
                wz[r][m] = g[(4 * kg + r) * 64 + p16 * 4 + m];
    }
    float fb1r[4];
    #pragma unroll
    for (int r = 0; r < 4; ++r) fb1r[r] = (4 * kg + r < 50) ? fb1[4 * kg + r] : 0.0f;

    const int yA = L_YCUR + yoffF(2 * b, i);       // own comp: cov state of batch b
    const int yB = L_YCUR + yoffF(2 * b + 1, i);   // own comp: ins state of batch b

    float y0a = 0.0f, y0b = 0.0f;   // own components of h_cov / h_ins
    __syncthreads();

    for (int t = 0; t < TT; ++t) {
        // ---- stage x and treat ----
        if (tid < 56) {
            int bb = tid / 28, c = tid - bb * 28;
            sm[L_XA + tid] = (c < 25) ? x[(blockIdx.x * 2 + bb) * (TT * 25) + t * 25 + c] : 0.0f;
        }
        if (i == 0) {
            const float* xp = x + bg * (TT * 25) + t * 25;
            sm[L_TR + b] = (xp[1] > 0.f || xp[2] > 0.f || xp[3] > 0.f || xp[4] > 0.f || xp[5] > 0.f) ? 1.0f : 0.0f;
        }
        const float sc = (dt[bg * (TT * 2) + t * 2 + 1] - dt[bg * (TT * 2) + t * 2]) * kDT_SC;
        __syncthreads();

        // ---- cell1: h_cov += tanh(xc@Wih1' + hc@Whh1' + b) ----
        {
            float acc = b1ci;
            acc = fmaf(Wih1T[i], sm[L_XA + b * 28 + 0], acc);
            #pragma unroll
            for (int j = 1; j < 19; ++j)
                acc = fmaf(Wih1T[j * 256 + i], sm[L_XA + b * 28 + 6 + j], acc);
            float4 a4 = {0.f, 0.f, 0.f, 0.f};
            #pragma unroll 4
            for (int jb = 0; jb < 64; ++jb) {
                float4 w = Whh1T4[jb * 256 + i];
                float4 h = ycur4[yoff4(2 * b, jb)];
                fma4(a4, w, h);
            }
            acc += rsum4(a4);
            y0a = y0a + fast_tanh(acc);
            sm[L_HC2 + b * 256 + i] = y0a;
        }
        __syncthreads();

        // ---- cell2: h_ins += tanh([xi,hc_new]@Wih2' + hi@Whh2' + b) ----
        {
            float acc = b2ci;
            #pragma unroll
            for (int j = 0; j < 5; ++j)
                acc = fmaf(Wih2aT[j * 256 + i], sm[L_XA + b * 28 + 1 + j], acc);
            float4 a4 = {0.f, 0.f, 0.f, 0.f};
            #pragma unroll 4
            for (int jb = 0; jb < 64; ++jb) {
                float4 w = Wih2bT4[jb * 256 + i];
                float4 h = hc24[b * 64 + jb];
                fma4(a4, w, h);
            }
            #pragma unroll 4
            for (int jb = 0; jb < 64; ++jb) {
                float4 w = Whh2T4[jb * 256 + i];
                float4 h = ycur4[yoff4(2 * b + 1, jb)];
                fma4(a4, w, h);
            }
            acc += rsum4(a4);
            y0b = y0b + fast_tanh(acc);
        }
        __syncthreads();
        // publish post-cell states
        sm[yA] = y0a;
        sm[yB] = y0b;

        // ---- ODE: 8 RK4 steps, 4 state vectors simultaneously ----
        for (int st = 0; st < NSTEP; ++st) {
            float acca = 0.f, accb = 0.f;
            #pragma unroll
            for (int e = 0; e < 4; ++e) {
                __syncthreads();   // ycur writes (cell publish / prev stage) visible
                // z-phase: 4-row x 16-col fW1 tile, both states of batch vg
                float pz[8];
                #pragma unroll
                for (int s = 0; s < 2; ++s) {
                    const float4* ys = ycur4 + (2 * vg + s) * 68 + (p16 >> 2) * 17 + (p16 & 3) * 4;
                    float4 P0 = {0,0,0,0}, P1 = {0,0,0,0}, P2 = {0,0,0,0}, P3 = {0,0,0,0};
                    #pragma unroll
                    for (int m = 0; m < 4; ++m) {
                        float4 y = ys[m];
                        fma4(P0, wz[0][m], y);
                        fma4(P1, wz[1][m], y);
                        fma4(P2, wz[2][m], y);
                        fma4(P3, wz[3][m], y);
                    }
                    pz[s * 4 + 0] = rsum4(P0); pz[s * 4 + 1] = rsum4(P1);
                    pz[s * 4 + 2] = rsum4(P2); pz[s * 4 + 3] = rsum4(P3);
                }
                #pragma unroll
                for (int r = 0; r < 8; ++r) pz[r] = allreduce16(pz[r]);
                if (p16 < 8) {
                    const int q = p16;
                    float a0 = (q & 1) ? pz[1] : pz[0];
                    float a1 = (q & 1) ? pz[3] : pz[2];
                    float a2 = (q & 1) ? pz[5] : pz[4];
                    float a3 = (q & 1) ? pz[7] : pz[6];
                    float b0s = (q & 2) ? a1 : a0;
                    float b1s = (q & 2) ? a3 : a2;
                    float vsum = (q & 4) ? b1s : b0s;
                    float f0 = (q & 1) ? fb1r[1] : fb1r[0];
                    float f1 = (q & 1) ? fb1r[3] : fb1r[2];
                    float fb = (q & 2) ? f1 : f0;
                    sm[L_Z + (2 * vg + (q >> 2)) * 64 + 4 * kg + (q & 3)] = fast_tanh(vsum + fb);
                }
                __syncthreads();   // z ready
                // update: du = (fW2.z + fb2)*sc for comp i of BOTH states of batch b.
                // wf2 row i read once from LDS (lane-consecutive); z reads wave-uniform.
                {
                    const float4* zva = (const float4*)(sm + L_Z + (2 * b) * 64);
                    const float4* zvb = (const float4*)(sm + L_Z + (2 * b + 1) * 64);
                    float4 A = {0,0,0,0}, Bq = {0,0,0,0};
                    #pragma unroll
                    for (int kb = 0; kb < 13; ++kb) {
                        float4 w = fw2l[kb * 256 + i];
                        fma4(A, w, zva[kb]);
                        fma4(Bq, w, zvb[kb]);
                    }
                    float dua = (fb2i + rsum4(A)) * sc;
                    float dub = (fb2i + rsum4(Bq)) * sc;
                    float ya, yb;
                    if (e == 0) {
                        acca = dua; accb = dub;
                        ya = fmaf(0.5f * HS, dua, y0a); yb = fmaf(0.5f * HS, dub, y0b);
                    } else if (e == 1) {
                        acca = fmaf(2.f, dua, acca); accb = fmaf(2.f, dub, accb);
                        ya = fmaf(0.5f * HS, dua, y0a); yb = fmaf(0.5f * HS, dub, y0b);
                    } else if (e == 2) {
                        acca = fmaf(2.f, dua, acca); accb = fmaf(2.f, dub, accb);
                        ya = fmaf(HS, dua, y0a); yb = fmaf(HS, dub, y0b);
                    } else {
                        acca += dua; accb += dub;
                        y0a = fmaf(HS / 6.f, acca, y0a); y0b = fmaf(HS / 6.f, accb, y0b);
                        ya = y0a; yb = y0b;
                    }
                    sm[yA] = ya;
                    sm[yB] = yb;
                }
            }
        }
        __syncthreads();   // final ycur (== h) visible

        // ---- output heads + reduction ----
        {
            float4 ao4 = {0.f,0.f,0.f,0.f}, ai4 = {0.f,0.f,0.f,0.f};
            #pragma unroll 4
            for (int jb = 0; jb < 64; ++jb) {
                float4 wo = oW1T4[jb * 256 + i];
                float4 hcv = ycur4[yoff4(2 * b, jb)];
                fma4(ao4, wo, hcv);
                float4 wi = iW1T4[jb * 256 + i];
                float4 hiv = ycur4[yoff4(2 * b + 1, jb)];
                fma4(ai4, wi, hiv);
            }
            float co = oW2i * fast_tanh(ob1i + rsum4(ao4));
            float ci = iW2i * fast_tanh(ib1i + rsum4(ai4));
            #pragma unroll
            for (int off = 32; off > 0; off >>= 1) {
                co += __shfl_xor(co, off);
                ci += __shfl_xor(ci, off);
            }
            if (lane == 0) { sm[L_RED + wv * 2] = co; sm[L_RED + wv * 2 + 1] = ci; }
        }
        __syncthreads();
        if (i == 0) {
            float sco = sm[L_RED + b * 8 + 0] + sm[L_RED + b * 8 + 2] + sm[L_RED + b * 8 + 4] + sm[L_RED + b * 8 + 6];
            float sci = sm[L_RED + b * 8 + 1] + sm[L_RED + b * 8 + 3] + sm[L_RED + b * 8 + 5] + sm[L_RED + b * 8 + 7];
            float muc = sco + ob2s;
            float mui = fmaxf(sci + ib2s, 0.0f);
            out[bg * TT + t] = muc - sm[L_TR + b] * mui;
        }
        __syncthreads();
    }
}

extern "C" void kernel_launch(void* const* d_in, const int* in_sizes, int n_in,
                              void* d_out, int out_size, void* d_ws, size_t ws_size,
                              hipStream_t stream) {
    const float* dt   = (const float*)d_in[0];
    const float* x    = (const float*)d_in[1];
    const float* Wih1 = (const float*)d_in[2];
    const float* Whh1 = (const float*)d_in[3];
    const float* bih1 = (const float*)d_in[4];
    const float* bhh1 = (const float*)d_in[5];
    const float* Wih2 = (const float*)d_in[6];
    const float* Whh2 = (const float*)d_in[7];
    const float* bih2 = (const float*)d_in[8];
    const float* bhh2 = (const float*)d_in[9];
    const float* oW1  = (const float*)d_in[10];
    const float* ob1  = (const float*)d_in[11];
    const float* oW2  = (const float*)d_in[12];
    const float* ob2  = (const float*)d_in[13];
    const float* iW1  = (const float*)d_in[14];
    const float* ib1  = (const float*)d_in[15];
    const float* iW2  = (const float*)d_in[16];
    const float* ib2  = (const float*)d_in[17];
    const float* fW1  = (const float*)d_in[18];
    const float* fb1  = (const float*)d_in[19];
    const float* fW2  = (const float*)d_in[20];
    const float* fb2  = (const float*)d_in[21];
    float* ws  = (float*)d_ws;
    float* out = (float*)d_out;

    if (ws_size < (size_t)WS_FLOATS * sizeof(float)) return;  // need ~1.46 MB scratch

    codernn_setup<<<WS_FLOATS / 256, 256, 0, stream>>>(Wih1, Whh1, bih1, bhh1, Wih2, Whh2,
                                                       bih2, bhh2, oW1, iW1, fW1, fW2, ws);

    codernn_main<<<256, 512, 0, stream>>>(dt, x, ws,
                                          ob1, oW2, ob2, ib1, iW2, ib2, fb1, fb2, out);
}

// Round 6
// 6559.990 us; speedup vs baseline: 2.0883x; 1.0067x over previous
//
#include <hip/hip_runtime.h>

// ---------------- problem constants ----------------
#define TT 100
#define HH 256
#define NSTEP 8
__device__ __constant__ float kDT_SC = 1.0f / 24.0f;
#define HS (0.125f)          // 1/NSTEP

// ---------------- d_ws layout (floats) ----------------
#define OFF_WHH1T4   0         // [64][256][4]
#define OFF_WIH1T    65536     // [20][256]
#define OFF_WIH2AT   70656     // [8][256]
#define OFF_WIH2BT4  72704     // [64][256][4]
#define OFF_WHH2T4   138240    // [64][256][4]
#define OFF_OW1T4    203776    // [64][256][4]
#define OFF_IW1T4    269312    // [64][256][4]
#define OFF_FW1R     334848    // [64][256] row-major, zero-padded rows >= 50
#define OFF_FW2T4    351232    // [13][256][4]
#define OFF_B1C      364544    // [256] bih1+bhh1
#define OFF_B2C      364800    // [256] bih2+bhh2
#define WS_FLOATS    365056

// ---------------- LDS layout (floats) ----------------
#define L_FW2   0        // [13][256][4] staged fW2T4 = 13312
#define L_YCUR  13312    // 2 rows * 272 (4 chunks of 68 = 64 data + 4 pad)
#define L_Z     13856    // 2 states * 64
#define L_HC2   13984    // 256
#define L_XA    14240    // 28
#define L_TR    14268    // 1
#define L_RED   14269    // 8
#define L_TOTAL 14277

__device__ __forceinline__ float fast_tanh(float v) {
    float e = __expf(2.0f * v);
    return 1.0f - 2.0f / (e + 1.0f);
}
__device__ __forceinline__ void fma4(float4& a, const float4 w, const float4 h) {
    a.x = fmaf(w.x, h.x, a.x); a.y = fmaf(w.y, h.y, a.y);
    a.z = fmaf(w.z, h.z, a.z); a.w = fmaf(w.w, h.w, a.w);
}
__device__ __forceinline__ float rsum4(const float4 a) { return (a.x + a.y) + (a.z + a.w); }
// padded ycur indexing: row v has 4 chunks of 68 floats (64 valid + 4 pad)
__device__ __forceinline__ int yoffF(int v, int j) { return v * 272 + (j >> 6) * 68 + (j & 63); }
__device__ __forceinline__ int yoff4(int v, int jb) { return v * 68 + (jb >> 4) * 17 + (jb & 15); }

// 16-lane allreduce via DPP rotate-add (row_ror:1,2,4,8) — pure VALU, no LDS pipe
template <int CTRL>
__device__ __forceinline__ float dpp_rr_add(float v) {
    int r = __builtin_amdgcn_update_dpp(0, __float_as_int(v), CTRL, 0xF, 0xF, false);
    return v + __int_as_float(r);
}
__device__ __forceinline__ float allreduce16(float v) {
    v = dpp_rr_add<0x121>(v);   // row_ror:1
    v = dpp_rr_add<0x122>(v);   // row_ror:2
    v = dpp_rr_add<0x124>(v);   // row_ror:4
    v = dpp_rr_add<0x128>(v);   // row_ror:8
    return v;
}

// ================= setup: repack weights into d_ws =================
__global__ void codernn_setup(const float* __restrict__ Wih1, const float* __restrict__ Whh1,
                              const float* __restrict__ bih1, const float* __restrict__ bhh1,
                              const float* __restrict__ Wih2, const float* __restrict__ Whh2,
                              const float* __restrict__ bih2, const float* __restrict__ bhh2,
                              const float* __restrict__ oW1, const float* __restrict__ iW1,
                              const float* __restrict__ fW1, const float* __restrict__ fW2,
                              float* __restrict__ ws) {
    int e = blockIdx.x * 256 + threadIdx.x;
    if (e >= WS_FLOATS) return;
    float v;
    if (e < OFF_WIH1T) {                 // Whh1T4
        int q = e; int jb = q >> 10, i = (q >> 2) & 255, dj = q & 3;
        v = Whh1[i * 256 + jb * 4 + dj];
    } else if (e < OFF_WIH2AT) {         // Wih1T [20][256]
        int q = e - OFF_WIH1T; int j = q >> 8, i = q & 255;
        v = (j < 19) ? Wih1[i * 19 + j] : 0.0f;
    } else if (e < OFF_WIH2BT4) {        // Wih2aT [8][256] (insulin cols 0..4)
        int q = e - OFF_WIH2AT; int j = q >> 8, i = q & 255;
        v = (j < 5) ? Wih2[i * 261 + j] : 0.0f;
    } else if (e < OFF_WHH2T4) {         // Wih2bT4 (cols 5..260)
        int q = e - OFF_WIH2BT4; int jb = q >> 10, i = (q >> 2) & 255, dj = q & 3;
        v = Wih2[i * 261 + 5 + jb * 4 + dj];
    } else if (e < OFF_OW1T4) {          // Whh2T4
        int q = e - OFF_WHH2T4; int jb = q >> 10, i = (q >> 2) & 255, dj = q & 3;
        v = Whh2[i * 256 + jb * 4 + dj];
    } else if (e < OFF_IW1T4) {          // oW1T4
        int q = e - OFF_OW1T4; int jb = q >> 10, i = (q >> 2) & 255, dj = q & 3;
        v = oW1[i * 256 + jb * 4 + dj];
    } else if (e < OFF_FW1R) {           // iW1T4
        int q = e - OFF_IW1T4; int jb = q >> 10, i = (q >> 2) & 255, dj = q & 3;
        v = iW1[i * 256 + jb * 4 + dj];
    } else if (e < OFF_FW2T4) {          // FW1R [64][256] row-major, zero-pad k>=50
        int q = e - OFF_FW1R; int k = q >> 8, j = q & 255;
        v = (k < 50) ? fW1[k * 256 + j] : 0.0f;
    } else if (e < OFF_B1C) {            // fW2T4 [13][256][4]: (kb*256+i)*4+dk = fW2[i][4kb+dk]
        int q = e - OFF_FW2T4; int kb = q >> 10, i = (q >> 2) & 255, dk = q & 3;
        int k = kb * 4 + dk;
        v = (k < 50) ? fW2[i * 50 + k] : 0.0f;
    } else if (e < OFF_B2C) {
        int q = e - OFF_B1C; v = bih1[q] + bhh1[q];
    } else {
        int q = e - OFF_B2C; v = bih2[q] + bhh2[q];
    }
    ws[e] = v;
}

// ================= main persistent kernel =================
// One batch element per 256-thread block; 512 blocks = 2 blocks/CU.
// states: 0 = cov, 1 = ins
__global__ __launch_bounds__(256, 2) void codernn_main(
    const float* __restrict__ dt, const float* __restrict__ x,
    const float* __restrict__ ws,
    const float* __restrict__ ob1, const float* __restrict__ oW2, const float* __restrict__ ob2,
    const float* __restrict__ ib1, const float* __restrict__ iW2, const float* __restrict__ ib2,
    const float* __restrict__ fb1, const float* __restrict__ fb2,
    float* __restrict__ out) {
    __shared__ float sm[L_TOTAL];
    const int tid = threadIdx.x;
    const int i = tid;               // owned H component
    const int bg = blockIdx.x;       // batch element
    const int lane = tid & 63, wv = tid >> 6;

    // stage fW2T4 into LDS; zero h state (ycur rows, incl. pads)
    for (int idx = tid; idx < 13312; idx += 256) sm[L_FW2 + idx] = ws[OFF_FW2T4 + idx];
    for (int idx = tid; idx < 544; idx += 256) sm[L_YCUR + idx] = 0.0f;

    // per-thread constants
    const float b1ci = ws[OFF_B1C + i];
    const float b2ci = ws[OFF_B2C + i];
    const float ob1i = ob1[i], ib1i = ib1[i];
    const float oW2i = oW2[i], iW2i = iW2[i];
    const float fb2i = fb2[i];
    const float ob2s = ob2[0], ib2s = ib2[0];

    // ---- z-phase role: (kg in 16, p16 in 16) ----
    const int kg = (tid >> 4) & 15;
    const int p16 = tid & 15;

    const float4* Whh1T4  = (const float4*)(ws + OFF_WHH1T4);
    const float*  Wih1T   = ws + OFF_WIH1T;
    const float*  Wih2aT  = ws + OFF_WIH2AT;
    const float4* Wih2bT4 = (const float4*)(ws + OFF_WIH2BT4);
    const float4* Whh2T4  = (const float4*)(ws + OFF_WHH2T4);
    const float4* oW1T4   = (const float4*)(ws + OFF_OW1T4);
    const float4* iW1T4   = (const float4*)(ws + OFF_IW1T4);
    const float4* ycur4   = (const float4*)(sm + L_YCUR);
    const float4* hc24    = (const float4*)(sm + L_HC2);
    const float4* fw2l    = (const float4*)(sm + L_FW2);

    // ---- register-cache fW1 only (64 VGPR): rows 4kg..4kg+3, cols 16*p16..+15
    float4 wz[4][4];
    {
        const float4* g = (const float4*)(ws + OFF_FW1R);
        #pragma unroll
        for (int r = 0; r < 4; ++r)
            #pragma unroll
            for (int m = 0; m < 4; ++m)
                wz[r][m] = g[(4 * kg + r) * 64 + p16 * 4 + m];
    }
    float fb1r[4];
    #pragma unroll
    for (int r = 0; r < 4; ++r) fb1r[r] = (4 * kg + r < 50) ? fb1[4 * kg + r] : 0.0f;

    const int yA = L_YCUR + yoffF(0, i);   // own comp: cov state
    const int yB = L_YCUR + yoffF(1, i);   // own comp: ins state

    float y0a = 0.0f, y0b = 0.0f;   // own components of h_cov / h_ins
    __syncthreads();

    for (int t = 0; t < TT; ++t) {
        // ---- stage x and treat ----
        if (tid < 28) {
            sm[L_XA + tid] = (tid < 25) ? x[bg * (TT * 25) + t * 25 + tid] : 0.0f;
        }
        if (i == 0) {
            const float* xp = x + bg * (TT * 25) + t * 25;
            sm[L_TR] = (xp[1] > 0.f || xp[2] > 0.f || xp[3] > 0.f || xp[4] > 0.f || xp[5] > 0.f) ? 1.0f : 0.0f;
        }
        const float sc = (dt[bg * (TT * 2) + t * 2 + 1] - dt[bg * (TT * 2) + t * 2]) * kDT_SC;
        __syncthreads();

        // ---- cell1: h_cov += tanh(xc@Wih1' + hc@Whh1' + b) ----
        {
            float acc = b1ci;
            acc = fmaf(Wih1T[i], sm[L_XA + 0], acc);
            #pragma unroll
            for (int j = 1; j < 19; ++j)
                acc = fmaf(Wih1T[j * 256 + i], sm[L_XA + 6 + j], acc);
            float4 a4 = {0.f, 0.f, 0.f, 0.f};
            #pragma unroll 4
            for (int jb = 0; jb < 64; ++jb) {
                float4 w = Whh1T4[jb * 256 + i];
                float4 h = ycur4[yoff4(0, jb)];
                fma4(a4, w, h);
            }
            acc += rsum4(a4);
            y0a = y0a + fast_tanh(acc);
            sm[L_HC2 + i] = y0a;
        }
        __syncthreads();

        // ---- cell2: h_ins += tanh([xi,hc_new]@Wih2' + hi@Whh2' + b) ----
        {
            float acc = b2ci;
            #pragma unroll
            for (int j = 0; j < 5; ++j)
                acc = fmaf(Wih2aT[j * 256 + i], sm[L_XA + 1 + j], acc);
            float4 a4 = {0.f, 0.f, 0.f, 0.f};
            #pragma unroll 4
            for (int jb = 0; jb < 64; ++jb) {
                float4 w = Wih2bT4[jb * 256 + i];
                float4 h = hc24[jb];
                fma4(a4, w, h);
            }
            #pragma unroll 4
            for (int jb = 0; jb < 64; ++jb) {
                float4 w = Whh2T4[jb * 256 + i];
                float4 h = ycur4[yoff4(1, jb)];
                fma4(a4, w, h);
            }
            acc += rsum4(a4);
            y0b = y0b + fast_tanh(acc);
        }
        __syncthreads();
        // publish post-cell states
        sm[yA] = y0a;
        sm[yB] = y0b;

        // ---- ODE: 8 RK4 steps, both state vectors simultaneously ----
        for (int st = 0; st < NSTEP; ++st) {
            float acca = 0.f, accb = 0.f;
            #pragma unroll
            for (int e = 0; e < 4; ++e) {
                __syncthreads();   // ycur writes (cell publish / prev stage) visible
                // z-phase: 4-row x 16-col fW1 tile, both states
                float pz[8];
                #pragma unroll
                for (int s = 0; s < 2; ++s) {
                    const float4* ys = ycur4 + s * 68 + (p16 >> 2) * 17 + (p16 & 3) * 4;
                    float4 P0 = {0,0,0,0}, P1 = {0,0,0,0}, P2 = {0,0,0,0}, P3 = {0,0,0,0};
                    #pragma unroll
                    for (int m = 0; m < 4; ++m) {
                        float4 y = ys[m];
                        fma4(P0, wz[0][m], y);
                        fma4(P1, wz[1][m], y);
                        fma4(P2, wz[2][m], y);
                        fma4(P3, wz[3][m], y);
                    }
                    pz[s * 4 + 0] = rsum4(P0); pz[s * 4 + 1] = rsum4(P1);
                    pz[s * 4 + 2] = rsum4(P2); pz[s * 4 + 3] = rsum4(P3);
                }
                #pragma unroll
                for (int r = 0; r < 8; ++r) pz[r] = allreduce16(pz[r]);
                if (p16 < 8) {
                    const int q = p16;
                    float a0 = (q & 1) ? pz[1] : pz[0];
                    float a1 = (q & 1) ? pz[3] : pz[2];
                    float a2 = (q & 1) ? pz[5] : pz[4];
                    float a3 = (q & 1) ? pz[7] : pz[6];
                    float b0s = (q & 2) ? a1 : a0;
                    float b1s = (q & 2) ? a3 : a2;
                    float vsum = (q & 4) ? b1s : b0s;
                    float f0 = (q & 1) ? fb1r[1] : fb1r[0];
                    float f1 = (q & 1) ? fb1r[3] : fb1r[2];
                    float fb = (q & 2) ? f1 : f0;
                    sm[L_Z + (q >> 2) * 64 + 4 * kg + (q & 3)] = fast_tanh(vsum + fb);
                }
                __syncthreads();   // z ready
                // update: du = (fW2.z + fb2)*sc for comp i of BOTH states.
                // wf2 row i read once from LDS (lane-consecutive); z reads wave-uniform.
                {
                    const float4* zva = (const float4*)(sm + L_Z);
                    const float4* zvb = (const float4*)(sm + L_Z + 64);
                    float4 A = {0,0,0,0}, Bq = {0,0,0,0};
                    #pragma unroll
                    for (int kb = 0; kb < 13; ++kb) {
                        float4 w = fw2l[kb * 256 + i];
                        fma4(A, w, zva[kb]);
                        fma4(Bq, w, zvb[kb]);
                    }
                    float dua = (fb2i + rsum4(A)) * sc;
                    float dub = (fb2i + rsum4(Bq)) * sc;
                    float ya, yb;
                    if (e == 0) {
                        acca = dua; accb = dub;
                        ya = fmaf(0.5f * HS, dua, y0a); yb = fmaf(0.5f * HS, dub, y0b);
                    } else if (e == 1) {
                        acca = fmaf(2.f, dua, acca); accb = fmaf(2.f, dub, accb);
                        ya = fmaf(0.5f * HS, dua, y0a); yb = fmaf(0.5f * HS, dub, y0b);
                    } else if (e == 2) {
                        acca = fmaf(2.f, dua, acca); accb = fmaf(2.f, dub, accb);
                        ya = fmaf(HS, dua, y0a); yb = fmaf(HS, dub, y0b);
                    } else {
                        acca += dua; accb += dub;
                        y0a = fmaf(HS / 6.f, acca, y0a); y0b = fmaf(HS / 6.f, accb, y0b);
                        ya = y0a; yb = y0b;
                    }
                    sm[yA] = ya;
                    sm[yB] = yb;
                }
            }
        }
        __syncthreads();   // final ycur (== h) visible

        // ---- output heads + reduction ----
        {
            float4 ao4 = {0.f,0.f,0.f,0.f}, ai4 = {0.f,0.f,0.f,0.f};
            #pragma unroll 4
            for (int jb = 0; jb < 64; ++jb) {
                float4 wo = oW1T4[jb * 256 + i];
                float4 hcv = ycur4[yoff4(0, jb)];
                fma4(ao4, wo, hcv);
                float4 wi = iW1T4[jb * 256 + i];
                float4 hiv = ycur4[yoff4(1, jb)];
                fma4(ai4, wi, hiv);
            }
            float co = oW2i * fast_tanh(ob1i + rsum4(ao4));
            float ci = iW2i * fast_tanh(ib1i + rsum4(ai4));
            #pragma unroll
            for (int off = 32; off > 0; off >>= 1) {
                co += __shfl_xor(co, off);
                ci += __shfl_xor(ci, off);
            }
            if (lane == 0) { sm[L_RED + wv * 2] = co; sm[L_RED + wv * 2 + 1] = ci; }
        }
        __syncthreads();
        if (i == 0) {
            float sco = sm[L_RED + 0] + sm[L_RED + 2] + sm[L_RED + 4] + sm[L_RED + 6];
            float sci = sm[L_RED + 1] + sm[L_RED + 3] + sm[L_RED + 5] + sm[L_RED + 7];
            float muc = sco + ob2s;
            float mui = fmaxf(sci + ib2s, 0.0f);
            out[bg * TT + t] = muc - sm[L_TR] * mui;
        }
        __syncthreads();
    }
}

extern "C" void kernel_launch(void* const* d_in, const int* in_sizes, int n_in,
                              void* d_out, int out_size, void* d_ws, size_t ws_size,
                              hipStream_t stream) {
    const float* dt   = (const float*)d_in[0];
    const float* x    = (const float*)d_in[1];
    const float* Wih1 = (const float*)d_in[2];
    const float* Whh1 = (const float*)d_in[3];
    const float* bih1 = (const float*)d_in[4];
    const float* bhh1 = (const float*)d_in[5];
    const float* Wih2 = (const float*)d_in[6];
    const float* Whh2 = (const float*)d_in[7];
    const float* bih2 = (const float*)d_in[8];
    const float* bhh2 = (const float*)d_in[9];
    const float* oW1  = (const float*)d_in[10];
    const float* ob1  = (const float*)d_in[11];
    const float* oW2  = (const float*)d_in[12];
    const float* ob2  = (const float*)d_in[13];
    const float* iW1  = (const float*)d_in[14];
    const float* ib1  = (const float*)d_in[15];
    const float* iW2  = (const float*)d_in[16];
    const float* ib2  = (const float*)d_in[17];
    const float* fW1  = (const float*)d_in[18];
    const float* fb1  = (const float*)d_in[19];
    const float* fW2  = (const float*)d_in[20];
    const float* fb2  = (const float*)d_in[21];
    float* ws  = (float*)d_ws;
    float* out = (float*)d_out;

    if (ws_size < (size_t)WS_FLOATS * sizeof(float)) return;  // need ~1.46 MB scratch

    codernn_setup<<<WS_FLOATS / 256, 256, 0, stream>>>(Wih1, Whh1, bih1, bhh1, Wih2, Whh2,
                                                       bih2, bhh2, oW1, iW1, fW1, fW2, ws);

    codernn_main<<<512, 256, 0, stream>>>(dt, x, ws,
                                          ob1, oW2, ob2, ib1, iW2, ib2, fb1, fb2, out);
}

// Round 8
// 5889.298 us; speedup vs baseline: 2.3261x; 1.1139x over previous
//
#include <hip/hip_runtime.h>

// ---------------- problem constants ----------------
#define TT 100
#define NSTEP 8
__device__ __constant__ float kDT_SC = 1.0f / 24.0f;
#define HS (0.125f)

typedef float f4 __attribute__((ext_vector_type(4)));
typedef float f2 __attribute__((ext_vector_type(2)));

// ---------------- d_ws layout (floats) ----------------
#define OFF_WHH1T4   0         // [64][256][4]
#define OFF_WIH1T    65536     // [20][256]
#define OFF_WIH2AT   70656     // [8][256]
#define OFF_WIH2BT4  72704     // [64][256][4]
#define OFF_WHH2T4   138240    // [64][256][4]
#define OFF_OW1T4    203776    // [64][256][4]
#define OFF_IW1T4    269312    // [64][256][4]
#define OFF_FW1R     334848    // [64][256] row-major, zero-padded rows >= 50
#define OFF_FW2T4    351232    // [13][256][4]
#define OFF_B1C      364544    // [256] bih1+bhh1
#define OFF_B2C      364800    // [256] bih2+bhh2
#define WS_FLOATS    365056

// ---------------- LDS layout (floats) ----------------
#define L_FW2   0        // [13][256][4] staged fW2T4 = 13312
#define L_YCUR  13312    // 2 rows * 272 (4 chunks of 68 = 64 data + 4 pad)
#define L_Z     13856    // 2 states * 64
#define L_HC2   13984    // 256
#define L_XA    14240    // 28
#define L_TR    14268    // 1
#define L_RED   14269    // 8
#define L_TOTAL 14277

__device__ __forceinline__ float fast_tanh(float v) {
    float e = __expf(2.0f * v);
    return 1.0f - 2.0f / (e + 1.0f);
}
__device__ __forceinline__ f2 vlo(f4 v) { return __builtin_shufflevector(v, v, 0, 1); }
__device__ __forceinline__ f2 vhi(f4 v) { return __builtin_shufflevector(v, v, 2, 3); }
// packed f32 fma: a += w*h elementwise (emits v_pk_fma_f32 on gfx90a+)
__device__ __forceinline__ void pkfma(f2& a, f2 w, f2 h) {
    a = __builtin_elementwise_fma(w, h, a);
}
__device__ __forceinline__ float rsum2(f2 a) { return a.x + a.y; }

// padded ycur indexing (f4 units): row v has 4 chunks of 17 f4 (16 data + 1 pad)
__device__ __forceinline__ int yoffF(int v, int j) { return v * 272 + (j >> 6) * 68 + (j & 63); }
__device__ __forceinline__ int yoff4(int v, int jb) { return v * 68 + (jb >> 4) * 17 + (jb & 15); }

// 16-lane allreduce via DPP rotate-add (row_ror:1,2,4,8)
template <int CTRL>
__device__ __forceinline__ float dpp_rr_add(float v) {
    int r = __builtin_amdgcn_update_dpp(0, __float_as_int(v), CTRL, 0xF, 0xF, false);
    return v + __int_as_float(r);
}
__device__ __forceinline__ float allreduce16(float v) {
    v = dpp_rr_add<0x121>(v);
    v = dpp_rr_add<0x122>(v);
    v = dpp_rr_add<0x124>(v);
    v = dpp_rr_add<0x128>(v);
    return v;
}

// ================= setup: repack weights into d_ws =================
__global__ void codernn_setup(const float* __restrict__ Wih1, const float* __restrict__ Whh1,
                              const float* __restrict__ bih1, const float* __restrict__ bhh1,
                              const float* __restrict__ Wih2, const float* __restrict__ Whh2,
                              const float* __restrict__ bih2, const float* __restrict__ bhh2,
                              const float* __restrict__ oW1, const float* __restrict__ iW1,
                              const float* __restrict__ fW1, const float* __restrict__ fW2,
                              float* __restrict__ ws) {
    int e = blockIdx.x * 256 + threadIdx.x;
    if (e >= WS_FLOATS) return;
    float v;
    if (e < OFF_WIH1T) {                 // Whh1T4
        int q = e; int jb = q >> 10, i = (q >> 2) & 255, dj = q & 3;
        v = Whh1[i * 256 + jb * 4 + dj];
    } else if (e < OFF_WIH2AT) {         // Wih1T [20][256]
        int q = e - OFF_WIH1T; int j = q >> 8, i = q & 255;
        v = (j < 19) ? Wih1[i * 19 + j] : 0.0f;
    } else if (e < OFF_WIH2BT4) {        // Wih2aT [8][256] (insulin cols 0..4)
        int q = e - OFF_WIH2AT; int j = q >> 8, i = q & 255;
        v = (j < 5) ? Wih2[i * 261 + j] : 0.0f;
    } else if (e < OFF_WHH2T4) {         // Wih2bT4 (cols 5..260)
        int q = e - OFF_WIH2BT4; int jb = q >> 10, i = (q >> 2) & 255, dj = q & 3;
        v = Wih2[i * 261 + 5 + jb * 4 + dj];
    } else if (e < OFF_OW1T4) {          // Whh2T4
        int q = e - OFF_WHH2T4; int jb = q >> 10, i = (q >> 2) & 255, dj = q & 3;
        v = Whh2[i * 256 + jb * 4 + dj];
    } else if (e < OFF_IW1T4) {          // oW1T4
        int q = e - OFF_OW1T4; int jb = q >> 10, i = (q >> 2) & 255, dj = q & 3;
        v = oW1[i * 256 + jb * 4 + dj];
    } else if (e < OFF_FW1R) {           // iW1T4
        int q = e - OFF_IW1T4; int jb = q >> 10, i = (q >> 2) & 255, dj = q & 3;
        v = iW1[i * 256 + jb * 4 + dj];
    } else if (e < OFF_FW2T4) {          // FW1R [64][256] row-major, zero-pad k>=50
        int q = e - OFF_FW1R; int k = q >> 8, j = q & 255;
        v = (k < 50) ? fW1[k * 256 + j] : 0.0f;
    } else if (e < OFF_B1C) {            // fW2T4 [13][256][4]: (kb*256+i)*4+dk = fW2[i][4kb+dk]
        int q = e - OFF_FW2T4; int kb = q >> 10, i = (q >> 2) & 255, dk = q & 3;
        int k = kb * 4 + dk;
        v = (k < 50) ? fW2[i * 50 + k] : 0.0f;
    } else if (e < OFF_B2C) {
        int q = e - OFF_B1C; v = bih1[q] + bhh1[q];
    } else {
        int q = e - OFF_B2C; v = bih2[q] + bhh2[q];
    }
    ws[e] = v;
}

// ================= main kernel =================
// One batch element per 256-thread block; 512 blocks = 2 blocks/CU.
__global__ __launch_bounds__(256, 2) void codernn_main(
    const float* __restrict__ dt, const float* __restrict__ x,
    const float* __restrict__ ws,
    const float* __restrict__ ob1, const float* __restrict__ oW2, const float* __restrict__ ob2,
    const float* __restrict__ ib1, const float* __restrict__ iW2, const float* __restrict__ ib2,
    const float* __restrict__ fb1, const float* __restrict__ fb2,
    float* __restrict__ out) {
    __shared__ float sm[L_TOTAL];
    const int tid = threadIdx.x;
    const int i = tid;               // owned H component
    const int bg = blockIdx.x;       // batch element
    const int lane = tid & 63, wv = tid >> 6;

    // stage fW2T4 into LDS; zero h state (ycur rows, incl. pads)
    for (int idx = tid; idx < 13312; idx += 256) sm[L_FW2 + idx] = ws[OFF_FW2T4 + idx];
    for (int idx = tid; idx < 544; idx += 256) sm[L_YCUR + idx] = 0.0f;

    // per-thread constants
    const float b1ci = ws[OFF_B1C + i];
    const float b2ci = ws[OFF_B2C + i];
    const float ob1i = ob1[i], ib1i = ib1[i];
    const float oW2i = oW2[i], iW2i = iW2[i];
    const float fb2i = fb2[i];
    const float ob2s = ob2[0], ib2s = ib2[0];

    // ---- z-phase role: (kg in 16, p16 in 16) ----
    const int kg = (tid >> 4) & 15;
    const int p16 = tid & 15;

    const f4* Whh1T4  = (const f4*)(ws + OFF_WHH1T4);
    const float* Wih1T  = ws + OFF_WIH1T;
    const float* Wih2aT = ws + OFF_WIH2AT;
    const f4* Wih2bT4 = (const f4*)(ws + OFF_WIH2BT4);
    const f4* Whh2T4  = (const f4*)(ws + OFF_WHH2T4);
    const f4* oW1T4   = (const f4*)(ws + OFF_OW1T4);
    const f4* iW1T4   = (const f4*)(ws + OFF_IW1T4);
    const f4* ycur4   = (const f4*)(sm + L_YCUR);
    const f4* hc24    = (const f4*)(sm + L_HC2);
    const f4* fw2l    = (const f4*)(sm + L_FW2);

    // ---- register-cache fW1 only (64 VGPR): rows 4kg..4kg+3, cols 16*p16..+15
    f4 wz[4][4];
    {
        const f4* g = (const f4*)(ws + OFF_FW1R);
        #pragma unroll
        for (int r = 0; r < 4; ++r)
            #pragma unroll
            for (int m = 0; m < 4; ++m)
                wz[r][m] = g[(4 * kg + r) * 64 + p16 * 4 + m];
    }
    float fb1r[4];
    #pragma unroll
    for (int r = 0; r < 4; ++r) fb1r[r] = (4 * kg + r < 50) ? fb1[4 * kg + r] : 0.0f;

    const int yA = L_YCUR + yoffF(0, i);   // own comp: cov state
    const int yB = L_YCUR + yoffF(1, i);   // own comp: ins state

    float y0a = 0.0f, y0b = 0.0f;
    __syncthreads();

    for (int t = 0; t < TT; ++t) {
        // ---- stage x and treat ----
        if (tid < 28) {
            sm[L_XA + tid] = (tid < 25) ? x[bg * (TT * 25) + t * 25 + tid] : 0.0f;
        }
        if (i == 0) {
            const float* xp = x + bg * (TT * 25) + t * 25;
            sm[L_TR] = (xp[1] > 0.f || xp[2] > 0.f || xp[3] > 0.f || xp[4] > 0.f || xp[5] > 0.f) ? 1.0f : 0.0f;
        }
        const float sc = (dt[bg * (TT * 2) + t * 2 + 1] - dt[bg * (TT * 2) + t * 2]) * kDT_SC;
        __syncthreads();

        // ---- cell1: h_cov += tanh(xc@Wih1' + hc@Whh1' + b) ----
        {
            float acc = b1ci;
            acc = fmaf(Wih1T[i], sm[L_XA + 0], acc);
            #pragma unroll
            for (int j = 1; j < 19; ++j)
                acc = fmaf(Wih1T[j * 256 + i], sm[L_XA + 6 + j], acc);
            f2 aL = {0.f, 0.f}, aH = {0.f, 0.f};
            #pragma unroll 4
            for (int jb = 0; jb < 64; ++jb) {
                f4 w = Whh1T4[jb * 256 + i];
                f4 h = ycur4[yoff4(0, jb)];
                pkfma(aL, vlo(w), vlo(h));
                pkfma(aH, vhi(w), vhi(h));
            }
            acc += rsum2(aL + aH);
            y0a = y0a + fast_tanh(acc);
            sm[L_HC2 + i] = y0a;
        }
        __syncthreads();

        // ---- cell2: h_ins += tanh([xi,hc_new]@Wih2' + hi@Whh2' + b) ----
        {
            float acc = b2ci;
            #pragma unroll
            for (int j = 0; j < 5; ++j)
                acc = fmaf(Wih2aT[j * 256 + i], sm[L_XA + 1 + j], acc);
            f2 aL = {0.f, 0.f}, aH = {0.f, 0.f};
            #pragma unroll 4
            for (int jb = 0; jb < 64; ++jb) {
                f4 w = Wih2bT4[jb * 256 + i];
                f4 h = hc24[jb];
                pkfma(aL, vlo(w), vlo(h));
                pkfma(aH, vhi(w), vhi(h));
            }
            #pragma unroll 4
            for (int jb = 0; jb < 64; ++jb) {
                f4 w = Whh2T4[jb * 256 + i];
                f4 h = ycur4[yoff4(1, jb)];
                pkfma(aL, vlo(w), vlo(h));
                pkfma(aH, vhi(w), vhi(h));
            }
            acc += rsum2(aL + aH);
            y0b = y0b + fast_tanh(acc);
        }
        __syncthreads();
        // publish post-cell states
        sm[yA] = y0a;
        sm[yB] = y0b;

        // ---- ODE: 8 RK4 steps, both state vectors simultaneously ----
        for (int st = 0; st < NSTEP; ++st) {
            float acca = 0.f, accb = 0.f;
            #pragma unroll
            for (int e = 0; e < 4; ++e) {
                __syncthreads();   // ycur writes (cell publish / prev stage) visible
                // z-phase: 4-row x 16-col fW1 tile, both states
                float pz[8];
                #pragma unroll
                for (int s = 0; s < 2; ++s) {
                    const f4* ys = ycur4 + s * 68 + (p16 >> 2) * 17 + (p16 & 3) * 4;
                    f2 P0l = {0,0}, P0h = {0,0}, P1l = {0,0}, P1h = {0,0};
                    f2 P2l = {0,0}, P2h = {0,0}, P3l = {0,0}, P3h = {0,0};
                    #pragma unroll
                    for (int m = 0; m < 4; ++m) {
                        f4 y = ys[m];
                        f2 yl = vlo(y), yh = vhi(y);
                        pkfma(P0l, vlo(wz[0][m]), yl); pkfma(P0h, vhi(wz[0][m]), yh);
                        pkfma(P1l, vlo(wz[1][m]), yl); pkfma(P1h, vhi(wz[1][m]), yh);
                        pkfma(P2l, vlo(wz[2][m]), yl); pkfma(P2h, vhi(wz[2][m]), yh);
                        pkfma(P3l, vlo(wz[3][m]), yl); pkfma(P3h, vhi(wz[3][m]), yh);
                    }
                    pz[s * 4 + 0] = rsum2(P0l + P0h);
                    pz[s * 4 + 1] = rsum2(P1l + P1h);
                    pz[s * 4 + 2] = rsum2(P2l + P2h);
                    pz[s * 4 + 3] = rsum2(P3l + P3h);
                }
                #pragma unroll
                for (int r = 0; r < 8; ++r) pz[r] = allreduce16(pz[r]);
                if (p16 < 8) {
                    const int q = p16;
                    float a0 = (q & 1) ? pz[1] : pz[0];
                    float a1 = (q & 1) ? pz[3] : pz[2];
                    float a2 = (q & 1) ? pz[5] : pz[4];
                    float a3 = (q & 1) ? pz[7] : pz[6];
                    float b0s = (q & 2) ? a1 : a0;
                    float b1s = (q & 2) ? a3 : a2;
                    float vsum = (q & 4) ? b1s : b0s;
                    float f0 = (q & 1) ? fb1r[1] : fb1r[0];
                    float f1 = (q & 1) ? fb1r[3] : fb1r[2];
                    float fb = (q & 2) ? f1 : f0;
                    sm[L_Z + (q >> 2) * 64 + 4 * kg + (q & 3)] = fast_tanh(vsum + fb);
                }
                __syncthreads();   // z ready
                // update: du = (fW2.z + fb2)*sc for comp i of BOTH states.
                {
                    const f4* zva = (const f4*)(sm + L_Z);
                    const f4* zvb = (const f4*)(sm + L_Z + 64);
                    f2 AL = {0,0}, AH = {0,0}, BL = {0,0}, BH = {0,0};
                    #pragma unroll
                    for (int kb = 0; kb < 13; ++kb) {
                        f4 w = fw2l[kb * 256 + i];
                        f4 za = zva[kb], zb = zvb[kb];
                        pkfma(AL, vlo(w), vlo(za)); pkfma(AH, vhi(w), vhi(za));
                        pkfma(BL, vlo(w), vlo(zb)); pkfma(BH, vhi(w), vhi(zb));
                    }
                    float dua = (fb2i + rsum2(AL + AH)) * sc;
                    float dub = (fb2i + rsum2(BL + BH)) * sc;
                    float ya, yb;
                    if (e == 0) {
                        acca = dua; accb = dub;
                        ya = fmaf(0.5f * HS, dua, y0a); yb = fmaf(0.5f * HS, dub, y0b);
                    } else if (e == 1) {
                        acca = fmaf(2.f, dua, acca); accb = fmaf(2.f, dub, accb);
                        ya = fmaf(0.5f * HS, dua, y0a); yb = fmaf(0.5f * HS, dub, y0b);
                    } else if (e == 2) {
                        acca = fmaf(2.f, dua, acca); accb = fmaf(2.f, dub, accb);
                        ya = fmaf(HS, dua, y0a); yb = fmaf(HS, dub, y0b);
                    } else {
                        acca += dua; accb += dub;
                        y0a = fmaf(HS / 6.f, acca, y0a); y0b = fmaf(HS / 6.f, accb, y0b);
                        ya = y0a; yb = y0b;
                    }
                    sm[yA] = ya;
                    sm[yB] = yb;
                }
            }
        }
        __syncthreads();   // final ycur (== h) visible

        // ---- output heads + reduction ----
        {
            f2 aoL = {0,0}, aoH = {0,0}, aiL = {0,0}, aiH = {0,0};
            #pragma unroll 4
            for (int jb = 0; jb < 64; ++jb) {
                f4 wo = oW1T4[jb * 256 + i];
                f4 hcv = ycur4[yoff4(0, jb)];
                pkfma(aoL, vlo(wo), vlo(hcv)); pkfma(aoH, vhi(wo), vhi(hcv));
                f4 wi = iW1T4[jb * 256 + i];
                f4 hiv = ycur4[yoff4(1, jb)];
                pkfma(aiL, vlo(wi), vlo(hiv)); pkfma(aiH, vhi(wi), vhi(hiv));
            }
            float co = oW2i * fast_tanh(ob1i + rsum2(aoL + aoH));
            float ci = iW2i * fast_tanh(ib1i + rsum2(aiL + aiH));
            #pragma unroll
            for (int off = 32; off > 0; off >>= 1) {
                co += __shfl_xor(co, off);
                ci += __shfl_xor(ci, off);
            }
            if (lane == 0) { sm[L_RED + wv * 2] = co; sm[L_RED + wv * 2 + 1] = ci; }
        }
        __syncthreads();
        if (i == 0) {
            float sco = sm[L_RED + 0] + sm[L_RED + 2] + sm[L_RED + 4] + sm[L_RED + 6];
            float sci = sm[L_RED + 1] + sm[L_RED + 3] + sm[L_RED + 5] + sm[L_RED + 7];
            float muc = sco + ob2s;
            float mui = fmaxf(sci + ib2s, 0.0f);
            out[bg * TT + t] = muc - sm[L_TR] * mui;
        }
        __syncthreads();
    }
}

extern "C" void kernel_launch(void* const* d_in, const int* in_sizes, int n_in,
                              void* d_out, int out_size, void* d_ws, size_t ws_size,
                              hipStream_t stream) {
    const float* dt   = (const float*)d_in[0];
    const float* x    = (const float*)d_in[1];
    const float* Wih1 = (const float*)d_in[2];
    const float* Whh1 = (const float*)d_in[3];
    const float* bih1 = (const float*)d_in[4];
    const float* bhh1 = (const float*)d_in[5];
    const float* Wih2 = (const float*)d_in[6];
    const float* Whh2 = (const float*)d_in[7];
    const float* bih2 = (const float*)d_in[8];
    const float* bhh2 = (const float*)d_in[9];
    const float* oW1  = (const float*)d_in[10];
    const float* ob1  = (const float*)d_in[11];
    const float* oW2  = (const float*)d_in[12];
    const float* ob2  = (const float*)d_in[13];
    const float* iW1  = (const float*)d_in[14];
    const float* ib1  = (const float*)d_in[15];
    const float* iW2  = (const float*)d_in[16];
    const float* ib2  = (const float*)d_in[17];
    const float* fW1  = (const float*)d_in[18];
    const float* fb1  = (const float*)d_in[19];
    const float* fW2  = (const float*)d_in[20];
    const float* fb2  = (const float*)d_in[21];
    float* ws  = (float*)d_ws;
    float* out = (float*)d_out;

    if (ws_size < (size_t)WS_FLOATS * sizeof(float)) return;

    codernn_setup<<<WS_FLOATS / 256, 256, 0, stream>>>(Wih1, Whh1, bih1, bhh1, Wih2, Whh2,
                                                       bih2, bhh2, oW1, iW1, fW1, fW2, ws);

    codernn_main<<<512, 256, 0, stream>>>(dt, x, ws,
                                          ob1, oW2, ob2, ib1, iW2, ib2, fb1, fb2, out);
}